// Round 3
// baseline (339.593 us; speedup 1.0000x reference)
//
#include <hip/hip_runtime.h>
#include <hip/hip_bf16.h>

#define N_NODES 4096
#define DIMC    256   // H*D, also K of both layer GEMMs
#define NHEADS  4
#define LOG2E   1.44269504f

typedef __attribute__((ext_vector_type(8))) short  short8;
typedef __attribute__((ext_vector_type(4))) short  short4v;
typedef __attribute__((ext_vector_type(4))) float  float4v;

union S8U { short8 v; unsigned int u[4]; };

#if __has_builtin(__builtin_amdgcn_exp2f)
#define EXP2(x) __builtin_amdgcn_exp2f(x)
#else
#define EXP2(x) exp2f(x)
#endif

__device__ inline unsigned short bf16_bits(__hip_bfloat16 b) {
  union { __hip_bfloat16 b; unsigned short u; } cv; cv.b = b; return cv.u;
}

// monotone float<->u32 encode for atomicMax over signed floats
__device__ inline unsigned fenc(float f) {
  unsigned u = __float_as_uint(f);
  return (u & 0x80000000u) ? ~u : (u | 0x80000000u);
}
__device__ inline float fdec(unsigned k) {
  unsigned u = (k & 0x80000000u) ? (k & 0x7FFFFFFFu) : ~k;
  return __uint_as_float(u);
}

// ---------------- adjacency -> bitmask (1 bit per edge) ----------------
__global__ __launch_bounds__(256) void pack_adj_kernel(
    const int* __restrict__ adj, unsigned long long* __restrict__ bits)
{
  int wid  = blockIdx.x * 4 + (threadIdx.x >> 6);
  int lane = threadIdx.x & 63;
  int row  = wid >> 6;
  int w64  = wid & 63;
  int v = adj[(size_t)row * N_NODES + w64 * 64 + lane];
  unsigned long long m = __ballot(v > 0);
  if (lane == 0) bits[row * 64 + w64] = m;
}

// ------------- fp32 -> split bf16 (hi + residual lo), elementwise --------
__global__ __launch_bounds__(256) void split_kernel(
    const float* __restrict__ in, __hip_bfloat16* __restrict__ hi,
    __hip_bfloat16* __restrict__ lo, int n)
{
  int i = blockIdx.x * 256 + threadIdx.x;
  if (i < n) {
    float v = in[i];
    __hip_bfloat16 h = __float2bfloat16(v);
    hi[i] = h;
    lo[i] = __float2bfloat16(v - __bfloat162float(h));
  }
}

// ------- fp32 transpose + split: in[B][R][C] -> outhi(/lo)[B][C][R] ------
// (weights only now). grid (R/32, C/32, B), block 256.
__global__ __launch_bounds__(256) void transpose_split_kernel(
    const float* __restrict__ in, __hip_bfloat16* __restrict__ outhi,
    __hip_bfloat16* __restrict__ outlo, int R, int C)
{
  __shared__ float tile[32][33];
  int t = threadIdx.x;
  int r0 = blockIdx.x * 32, c0 = blockIdx.y * 32;
  size_t base = (size_t)blockIdx.z * R * C;
  int tr = t >> 3, tc = (t & 7) * 4;
  const float* ip = in + base;
  float4v v = *reinterpret_cast<const float4v*>(ip + (size_t)(r0 + tr) * C + c0 + tc);
#pragma unroll
  for (int k = 0; k < 4; ++k) tile[tr][tc + k] = v[k];
  __syncthreads();
  short4v oh, ol;
#pragma unroll
  for (int k = 0; k < 4; ++k) {
    float f = tile[tc + k][tr];
    __hip_bfloat16 hb = __float2bfloat16(f);
    __hip_bfloat16 lb = __float2bfloat16(f - __bfloat162float(hb));
    oh[k] = (short)bf16_bits(hb);
    ol[k] = (short)bf16_bits(lb);
  }
  size_t oidx = base + (size_t)(c0 + tr) * R + r0 + tc;
  *reinterpret_cast<short4v*>(reinterpret_cast<unsigned short*>(outhi) + oidx) = oh;
  if (outlo)
    *reinterpret_cast<short4v*>(reinterpret_cast<unsigned short*>(outlo) + oidx) = ol;
}

// ------------- h GEMM (split-bf16) + fused transpose epilogue ------------
// out[n][c] fp32 row-major AND hTh[c][n] bf16 (hi) in one kernel.
// grid (128,8), block 256 (4 waves, 16x16 sub-tiles).
__global__ __launch_bounds__(256) void gemm_kernel(
    const __hip_bfloat16* __restrict__ Xhi, const __hip_bfloat16* __restrict__ Xlo,
    const __hip_bfloat16* __restrict__ WThi, const __hip_bfloat16* __restrict__ WTlo,
    float* __restrict__ out, __hip_bfloat16* __restrict__ hTh)
{
  __shared__ float tl[32][33];
  int t = threadIdx.x;
  int wv = t >> 6, lane = t & 63, quad = lane >> 4, col = lane & 15;
  int br = blockIdx.x * 32, bc = blockIdx.y * 32;
  int r0 = br + (wv >> 1) * 16;
  int c0 = bc + (wv & 1) * 16;
  float4v acc = {0, 0, 0, 0};
  const unsigned short* Xh = reinterpret_cast<const unsigned short*>(Xhi);
  const unsigned short* Xl = reinterpret_cast<const unsigned short*>(Xlo);
  const unsigned short* Wh = reinterpret_cast<const unsigned short*>(WThi);
  const unsigned short* Wl = reinterpret_cast<const unsigned short*>(WTlo);
#pragma unroll
  for (int k0 = 0; k0 < DIMC; k0 += 32) {
    size_t ao = (size_t)(r0 + col) * DIMC + k0 + quad * 8;
    size_t bo = (size_t)(c0 + col) * DIMC + k0 + quad * 8;
    short8 ah = *reinterpret_cast<const short8*>(Xh + ao);
    short8 al = *reinterpret_cast<const short8*>(Xl + ao);
    short8 bh = *reinterpret_cast<const short8*>(Wh + bo);
    short8 bl = *reinterpret_cast<const short8*>(Wl + bo);
    acc = __builtin_amdgcn_mfma_f32_16x16x32_bf16(ah, bh, acc, 0, 0, 0);
    acc = __builtin_amdgcn_mfma_f32_16x16x32_bf16(ah, bl, acc, 0, 0, 0);
    acc = __builtin_amdgcn_mfma_f32_16x16x32_bf16(al, bh, acc, 0, 0, 0);
  }
  int lr = (wv >> 1) * 16 + quad * 4, lc = (wv & 1) * 16 + col;
#pragma unroll
  for (int r = 0; r < 4; ++r) {
    out[(size_t)(r0 + quad * 4 + r) * DIMC + c0 + col] = acc[r];
    tl[lr + r][lc] = acc[r];
  }
  __syncthreads();
  int tr = t >> 3, tc = (t & 7) * 4;
  short4v oh;
#pragma unroll
  for (int k = 0; k < 4; ++k)
    oh[k] = (short)bf16_bits(__float2bfloat16(tl[tc + k][tr]));
  *reinterpret_cast<short4v*>(
      reinterpret_cast<unsigned short*>(hTh) + (size_t)(bc + tr) * N_NODES + br + tc) = oh;
}

// ---- f1/f2 (log2-scaled) + fused per-head global max (encoded atomic) ---
// grid 1024, block 256: wave per node.
__global__ __launch_bounds__(256) void fvec_kernel(
    const float* __restrict__ hA, const float* __restrict__ a,
    float* __restrict__ f1L, float* __restrict__ f2L,
    unsigned* __restrict__ f2enc)
{
  __shared__ float bm[4][4];  // [wave][head]
  int t = threadIdx.x, wv = t >> 6, lane = t & 63;
  int n = blockIdx.x * 4 + wv;
  int h = lane >> 4, d4 = (lane & 15) * 4;
  float4v v = *reinterpret_cast<const float4v*>(hA + (size_t)n * DIMC + lane * 4);
  const float* ah = a + h * 128;
  float s1 = v[0]*ah[d4] + v[1]*ah[d4+1] + v[2]*ah[d4+2] + v[3]*ah[d4+3];
  float s2 = v[0]*ah[64+d4] + v[1]*ah[64+d4+1] + v[2]*ah[64+d4+2] + v[3]*ah[64+d4+3];
#pragma unroll
  for (int o = 8; o >= 1; o >>= 1) {
    s1 += __shfl_xor(s1, o);
    s2 += __shfl_xor(s2, o);
  }
  float s2s = s2 * LOG2E;
  if ((lane & 15) == 0) {
    f1L[h * N_NODES + n] = s1 * LOG2E;
    f2L[h * N_NODES + n] = s2s;
    bm[wv][h] = s2s;
  }
  __syncthreads();
  if (t < 4) {
    float m = fmaxf(fmaxf(bm[0][t], bm[1][t]), fmaxf(bm[2][t], bm[3][t]));
    atomicMax(f2enc + t, fenc(m));
  }
}

// ------ fused masked-softmax attention, barrier-free j-sweep -------------
// grid (256, 4) = (16-row i-tile, head). block 256 = 4 waves.
// All waves cover the SAME 16 rows; wave wv sweeps j in [wv*1024,(wv+1)*1024)
// (no weight duplication). V-fragments (B-operand) load DIRECTLY from global
// (hTh slice is 512 KB -> L2-resident): no LDS tile, no __syncthreads in the
// main loop -> 16 independent waves/CU hide all latency. One LDS reduce at
// the end combines the 4 per-wave partials, then normalize+ELU+final write.
__global__ __launch_bounds__(256, 4) void attn_kernel(
    const __hip_bfloat16* __restrict__ hThi,   // [256][4096], row c = h*64+d
    const float* __restrict__ f1L, const float* __restrict__ f2L,
    const unsigned* __restrict__ f2enc,
    const unsigned long long* __restrict__ bits64, // [4096][64]
    float* __restrict__ outf, __hip_bfloat16* __restrict__ outhi,
    __hip_bfloat16* __restrict__ outlo)
{
  __shared__ float part[4][16][68];  // [wave][row][64 d + denom @64]; 17.4 KB
  int t = threadIdx.x;
  int wv = t >> 6, lane = t & 63, quad = lane >> 4, col = lane & 15;
  int it = blockIdx.x, h = blockIdx.y;
  int i0 = it * 16;
  int irow = i0 + col;               // weight row handled by this lane

  float f2m = fdec(f2enc[h]);
  float f1i = f1L[h * N_NODES + irow];
  float s0 = f1i + f2m;
  float m = fmaxf(s0, 0.2f * s0);    // lrelu monotone -> valid upper-bound shift
  float f1m = f1i - m;               // s' = f1m + fv;  lr-m = max(s', 0.2*s'+cm)
  float cm = -0.8f * m;

  const unsigned short* H =
      reinterpret_cast<const unsigned short*>(hThi) + (size_t)h * 64 * N_NODES;
  const float* f2h = f2L + h * N_NODES;
  const unsigned long long* brow = bits64 + (size_t)irow * 64;

  float4v acc[4] = {{0,0,0,0},{0,0,0,0},{0,0,0,0},{0,0,0,0}};
  float4v accl = {0, 0, 0, 0};
  S8U ones;
  ones.u[0] = ones.u[1] = ones.u[2] = ones.u[3] = 0x3F803F80u; // bf16 1.0 x2

  int jbase = wv * (N_NODES / 4);    // private 1024-j range per wave

  for (int ji = 0; ji < 16; ++ji) {  // 16 x 64-j steps, no barriers
    int j0 = jbase + ji * 64;
    unsigned long long wq = brow[j0 >> 6] >> (quad * 8);
    unsigned int wb0 = (unsigned int)wq;
    unsigned int wb1 = (unsigned int)(wq >> 32);
#pragma unroll
    for (int jh = 0; jh < 2; ++jh) {
      unsigned int wb = jh ? wb1 : wb0;
      const float* fp = f2h + j0 + jh * 32 + quad * 8;
      float4v fa = *reinterpret_cast<const float4v*>(fp);
      float4v fb = *reinterpret_cast<const float4v*>(fp + 4);
      float w[8];
#pragma unroll
      for (int jj = 0; jj < 8; ++jj) {
        float fv = (jj < 4) ? fa[jj] : fb[jj - 4];
        float sp = f1m + fv;
        float tb = __builtin_fmaf(0.2f, sp, cm);
        float lr = fmaxf(sp, tb);
        float e = EXP2(lr);
        w[jj] = (wb & (1u << jj)) ? e : 0.0f;
      }
      S8U afr;
#pragma unroll
      for (int k2 = 0; k2 < 4; ++k2)   // truncate-pack two fp32 -> bf16x2
        afr.u[k2] = __builtin_amdgcn_perm(__float_as_uint(w[2 * k2 + 1]),
                                          __float_as_uint(w[2 * k2]),
                                          0x07060302u);
      int jj0 = j0 + jh * 32 + quad * 8;
#pragma unroll
      for (int db = 0; db < 4; ++db) {
        short8 bfr = *reinterpret_cast<const short8*>(
            H + (size_t)(db * 16 + col) * N_NODES + jj0);
        acc[db] = __builtin_amdgcn_mfma_f32_16x16x32_bf16(afr.v, bfr, acc[db], 0, 0, 0);
      }
      accl = __builtin_amdgcn_mfma_f32_16x16x32_bf16(afr.v, ones.v, accl, 0, 0, 0);
    }
  }

  // C/D layout: col=lane&15 (d sub-col), row=quad*4+reg (i). Park partials.
#pragma unroll
  for (int db = 0; db < 4; ++db)
#pragma unroll
    for (int r = 0; r < 4; ++r)
      part[wv][quad * 4 + r][db * 16 + col] = acc[db][r];
  if (col == 0) {
#pragma unroll
    for (int r = 0; r < 4; ++r) part[wv][quad * 4 + r][64] = accl[r];
  }
  __syncthreads();

  // 256 threads: thread -> (row = t>>4, 4 d at (t&15)*4). Sum 4 wave partials.
  int row = t >> 4, dd = (t & 15) * 4;
  float4v s = {0, 0, 0, 0};
  float l = 0.f;
#pragma unroll
  for (int w2 = 0; w2 < 4; ++w2) {
    float4v pv = *reinterpret_cast<const float4v*>(&part[w2][row][dd]);
    s += pv;
    l += part[w2][row][64];
  }
  float rl = 1.0f / l;
  float o[4];
#pragma unroll
  for (int r = 0; r < 4; ++r) {
    float v = s[r] * rl;
    o[r] = v > 0.f ? v : EXP2(v * LOG2E) - 1.0f;
  }
  size_t oo = (size_t)(i0 + row) * DIMC + h * 64 + dd;
  if (outf) {
    *reinterpret_cast<float4v*>(outf + oo) = {o[0], o[1], o[2], o[3]};
  } else {
    short4v ohv, olv;
#pragma unroll
    for (int r = 0; r < 4; ++r) {
      __hip_bfloat16 hb = __float2bfloat16(o[r]);
      ohv[r] = (short)bf16_bits(hb);
      olv[r] = (short)bf16_bits(__float2bfloat16(o[r] - __bfloat162float(hb)));
    }
    *reinterpret_cast<short4v*>(reinterpret_cast<unsigned short*>(outhi) + oo) = ohv;
    *reinterpret_cast<short4v*>(reinterpret_cast<unsigned short*>(outlo) + oo) = olv;
  }
}

extern "C" void kernel_launch(void* const* d_in, const int* in_sizes, int n_in,
                              void* d_out, int out_size, void* d_ws, size_t ws_size,
                              hipStream_t stream)
{
  // inputs: t, x, adj, W1, a1, W2, a2  (fp32 except adj int32)
  const float* x   = (const float*)d_in[1];
  const int*   adj = (const int*)d_in[2];
  const float* W1  = (const float*)d_in[3];
  const float* a1  = (const float*)d_in[4];
  const float* W2  = (const float*)d_in[5];
  const float* a2  = (const float*)d_in[6];

  char* ws = (char*)d_ws;
  size_t off = 0;
  auto alloc = [&](size_t b) { size_t o = off; off = (off + b + 255) & ~255ULL; return o; };
  size_t o_bits = alloc((size_t)N_NODES * 64 * 8);          // 2 MB bitmask
  size_t o_w1h  = alloc((size_t)DIMC * DIMC * 2);
  size_t o_w1l  = alloc((size_t)DIMC * DIMC * 2);
  size_t o_w2h  = alloc((size_t)DIMC * DIMC * 2);
  size_t o_w2l  = alloc((size_t)DIMC * DIMC * 2);
  size_t o_xh   = alloc((size_t)N_NODES * DIMC * 2);
  size_t o_xl   = alloc((size_t)N_NODES * DIMC * 2);
  size_t o_hA   = alloc((size_t)N_NODES * DIMC * 4);        // h fp32 row-major
  size_t o_hTh  = alloc((size_t)N_NODES * DIMC * 2);        // h^T hi only
  size_t o_x2h  = alloc((size_t)N_NODES * DIMC * 2);
  size_t o_x2l  = alloc((size_t)N_NODES * DIMC * 2);
  size_t o_f1   = alloc((size_t)NHEADS * N_NODES * 4);
  size_t o_f2   = alloc((size_t)NHEADS * N_NODES * 4);
  size_t o_fm   = alloc(256);                               // 2 layers x 4 u32 (encoded max)

  unsigned long long* bits = (unsigned long long*)(ws + o_bits);
  __hip_bfloat16* w1h = (__hip_bfloat16*)(ws + o_w1h);
  __hip_bfloat16* w1l = (__hip_bfloat16*)(ws + o_w1l);
  __hip_bfloat16* w2h = (__hip_bfloat16*)(ws + o_w2h);
  __hip_bfloat16* w2l = (__hip_bfloat16*)(ws + o_w2l);
  __hip_bfloat16* xh  = (__hip_bfloat16*)(ws + o_xh);
  __hip_bfloat16* xl  = (__hip_bfloat16*)(ws + o_xl);
  float*          hA  = (float*)(ws + o_hA);
  __hip_bfloat16* hTh = (__hip_bfloat16*)(ws + o_hTh);
  __hip_bfloat16* x2h = (__hip_bfloat16*)(ws + o_x2h);
  __hip_bfloat16* x2l = (__hip_bfloat16*)(ws + o_x2l);
  float* f1p = (float*)(ws + o_f1);
  float* f2p = (float*)(ws + o_f2);
  unsigned* fme = (unsigned*)(ws + o_fm);

  hipMemsetAsync(ws + o_fm, 0, 64, stream);  // encoded-max init (monotone min)
  pack_adj_kernel<<<N_NODES * 64 / 4, 256, 0, stream>>>(adj, bits);
  transpose_split_kernel<<<dim3(8, 2, 4), 256, 0, stream>>>(W1, w1h, w1l, 256, 64);
  transpose_split_kernel<<<dim3(8, 2, 4), 256, 0, stream>>>(W2, w2h, w2l, 256, 64);
  split_kernel<<<N_NODES * DIMC / 256, 256, 0, stream>>>(x, xh, xl, N_NODES * DIMC);

  auto layer = [&](const __hip_bfloat16* xih, const __hip_bfloat16* xil,
                   const __hip_bfloat16* wth, const __hip_bfloat16* wtl,
                   const float* av, unsigned* fmk, float* outf,
                   __hip_bfloat16* oh, __hip_bfloat16* ol) {
    gemm_kernel<<<dim3(128, 8), 256, 0, stream>>>(xih, xil, wth, wtl, hA, hTh);
    fvec_kernel<<<1024, 256, 0, stream>>>(hA, av, f1p, f2p, fmk);
    attn_kernel<<<dim3(256, 4), 256, 0, stream>>>(hTh, f1p, f2p, fmk, bits,
                                                  outf, oh, ol);
  };

  layer(xh,  xl,  w1h, w1l, a1, fme,     nullptr,        x2h, x2l);
  layer(x2h, x2l, w2h, w2l, a2, fme + 4, (float*)d_out,  nullptr, nullptr);
}

// Round 4
// 338.948 us; speedup vs baseline: 1.0019x; 1.0019x over previous
//
#include <hip/hip_runtime.h>
#include <hip/hip_bf16.h>

#define N_NODES 4096
#define DIMC    256   // H*D, also K of both layer GEMMs
#define NHEADS  4
#define LOG2E   1.44269504f

typedef __attribute__((ext_vector_type(8))) short  short8;
typedef __attribute__((ext_vector_type(4))) short  short4v;
typedef __attribute__((ext_vector_type(4))) float  float4v;

union S8U { short8 v; unsigned int u[4]; };

#if __has_builtin(__builtin_amdgcn_exp2f)
#define EXP2(x) __builtin_amdgcn_exp2f(x)
#else
#define EXP2(x) exp2f(x)
#endif

__device__ inline unsigned short bf16_bits(__hip_bfloat16 b) {
  union { __hip_bfloat16 b; unsigned short u; } cv; cv.b = b; return cv.u;
}

// monotone float<->u32 encode for atomicMax over signed floats
__device__ inline unsigned fenc(float f) {
  unsigned u = __float_as_uint(f);
  return (u & 0x80000000u) ? ~u : (u | 0x80000000u);
}
__device__ inline float fdec(unsigned k) {
  unsigned u = (k & 0x80000000u) ? (k & 0x7FFFFFFFu) : ~k;
  return __uint_as_float(u);
}

// ---------------- adjacency -> bitmask (1 bit per edge) ----------------
__global__ __launch_bounds__(256) void pack_adj_kernel(
    const int* __restrict__ adj, unsigned long long* __restrict__ bits)
{
  int wid  = blockIdx.x * 4 + (threadIdx.x >> 6);
  int lane = threadIdx.x & 63;
  int row  = wid >> 6;
  int w64  = wid & 63;
  int v = adj[(size_t)row * N_NODES + w64 * 64 + lane];
  unsigned long long m = __ballot(v > 0);
  if (lane == 0) bits[row * 64 + w64] = m;
}

// ------------- fp32 -> split bf16 (hi + residual lo), elementwise --------
__global__ __launch_bounds__(256) void split_kernel(
    const float* __restrict__ in, __hip_bfloat16* __restrict__ hi,
    __hip_bfloat16* __restrict__ lo, int n)
{
  int i = blockIdx.x * 256 + threadIdx.x;
  if (i < n) {
    float v = in[i];
    __hip_bfloat16 h = __float2bfloat16(v);
    hi[i] = h;
    lo[i] = __float2bfloat16(v - __bfloat162float(h));
  }
}

// ------- fp32 transpose + split: in[B][R][C] -> outhi(/lo)[B][C][R] ------
// (weights only now). grid (R/32, C/32, B), block 256.
__global__ __launch_bounds__(256) void transpose_split_kernel(
    const float* __restrict__ in, __hip_bfloat16* __restrict__ outhi,
    __hip_bfloat16* __restrict__ outlo, int R, int C)
{
  __shared__ float tile[32][33];
  int t = threadIdx.x;
  int r0 = blockIdx.x * 32, c0 = blockIdx.y * 32;
  size_t base = (size_t)blockIdx.z * R * C;
  int tr = t >> 3, tc = (t & 7) * 4;
  const float* ip = in + base;
  float4v v = *reinterpret_cast<const float4v*>(ip + (size_t)(r0 + tr) * C + c0 + tc);
#pragma unroll
  for (int k = 0; k < 4; ++k) tile[tr][tc + k] = v[k];
  __syncthreads();
  short4v oh, ol;
#pragma unroll
  for (int k = 0; k < 4; ++k) {
    float f = tile[tc + k][tr];
    __hip_bfloat16 hb = __float2bfloat16(f);
    __hip_bfloat16 lb = __float2bfloat16(f - __bfloat162float(hb));
    oh[k] = (short)bf16_bits(hb);
    ol[k] = (short)bf16_bits(lb);
  }
  size_t oidx = base + (size_t)(c0 + tr) * R + r0 + tc;
  *reinterpret_cast<short4v*>(reinterpret_cast<unsigned short*>(outhi) + oidx) = oh;
  if (outlo)
    *reinterpret_cast<short4v*>(reinterpret_cast<unsigned short*>(outlo) + oidx) = ol;
}

// ------------- h GEMM (split-bf16) + fused transpose epilogue ------------
// out[n][c] fp32 row-major AND hTh[c][n] bf16 (hi) in one kernel.
// grid (128,8), block 256 (4 waves, 16x16 sub-tiles).
__global__ __launch_bounds__(256) void gemm_kernel(
    const __hip_bfloat16* __restrict__ Xhi, const __hip_bfloat16* __restrict__ Xlo,
    const __hip_bfloat16* __restrict__ WThi, const __hip_bfloat16* __restrict__ WTlo,
    float* __restrict__ out, __hip_bfloat16* __restrict__ hTh)
{
  __shared__ float tl[32][33];
  int t = threadIdx.x;
  int wv = t >> 6, lane = t & 63, quad = lane >> 4, col = lane & 15;
  int br = blockIdx.x * 32, bc = blockIdx.y * 32;
  int r0 = br + (wv >> 1) * 16;
  int c0 = bc + (wv & 1) * 16;
  float4v acc = {0, 0, 0, 0};
  const unsigned short* Xh = reinterpret_cast<const unsigned short*>(Xhi);
  const unsigned short* Xl = reinterpret_cast<const unsigned short*>(Xlo);
  const unsigned short* Wh = reinterpret_cast<const unsigned short*>(WThi);
  const unsigned short* Wl = reinterpret_cast<const unsigned short*>(WTlo);
#pragma unroll
  for (int k0 = 0; k0 < DIMC; k0 += 32) {
    size_t ao = (size_t)(r0 + col) * DIMC + k0 + quad * 8;
    size_t bo = (size_t)(c0 + col) * DIMC + k0 + quad * 8;
    short8 ah = *reinterpret_cast<const short8*>(Xh + ao);
    short8 al = *reinterpret_cast<const short8*>(Xl + ao);
    short8 bh = *reinterpret_cast<const short8*>(Wh + bo);
    short8 bl = *reinterpret_cast<const short8*>(Wl + bo);
    acc = __builtin_amdgcn_mfma_f32_16x16x32_bf16(ah, bh, acc, 0, 0, 0);
    acc = __builtin_amdgcn_mfma_f32_16x16x32_bf16(ah, bl, acc, 0, 0, 0);
    acc = __builtin_amdgcn_mfma_f32_16x16x32_bf16(al, bh, acc, 0, 0, 0);
  }
  int lr = (wv >> 1) * 16 + quad * 4, lc = (wv & 1) * 16 + col;
#pragma unroll
  for (int r = 0; r < 4; ++r) {
    out[(size_t)(r0 + quad * 4 + r) * DIMC + c0 + col] = acc[r];
    tl[lr + r][lc] = acc[r];
  }
  __syncthreads();
  int tr = t >> 3, tc = (t & 7) * 4;
  short4v oh;
#pragma unroll
  for (int k = 0; k < 4; ++k)
    oh[k] = (short)bf16_bits(__float2bfloat16(tl[tc + k][tr]));
  *reinterpret_cast<short4v*>(
      reinterpret_cast<unsigned short*>(hTh) + (size_t)(bc + tr) * N_NODES + br + tc) = oh;
}

// ---- f1/f2 (log2-scaled) + fused per-head global max (encoded atomic) ---
// grid 1024, block 256: wave per node.
__global__ __launch_bounds__(256) void fvec_kernel(
    const float* __restrict__ hA, const float* __restrict__ a,
    float* __restrict__ f1L, float* __restrict__ f2L,
    unsigned* __restrict__ f2enc)
{
  __shared__ float bm[4][4];  // [wave][head]
  int t = threadIdx.x, wv = t >> 6, lane = t & 63;
  int n = blockIdx.x * 4 + wv;
  int h = lane >> 4, d4 = (lane & 15) * 4;
  float4v v = *reinterpret_cast<const float4v*>(hA + (size_t)n * DIMC + lane * 4);
  const float* ah = a + h * 128;
  float s1 = v[0]*ah[d4] + v[1]*ah[d4+1] + v[2]*ah[d4+2] + v[3]*ah[d4+3];
  float s2 = v[0]*ah[64+d4] + v[1]*ah[64+d4+1] + v[2]*ah[64+d4+2] + v[3]*ah[64+d4+3];
#pragma unroll
  for (int o = 8; o >= 1; o >>= 1) {
    s1 += __shfl_xor(s1, o);
    s2 += __shfl_xor(s2, o);
  }
  float s2s = s2 * LOG2E;
  if ((lane & 15) == 0) {
    f1L[h * N_NODES + n] = s1 * LOG2E;
    f2L[h * N_NODES + n] = s2s;
    bm[wv][h] = s2s;
  }
  __syncthreads();
  if (t < 4) {
    float m = fmaxf(fmaxf(bm[0][t], bm[1][t]), fmaxf(bm[2][t], bm[3][t]));
    atomicMax(f2enc + t, fenc(m));
  }
}

// ------ fused masked-softmax attention, software-pipelined j-sweep -------
// grid (128, 4) = (32-row i-tile, head). block 512 = 8 waves:
// wave wv -> row-group rg=wv>>2 (16 rows), j-quarter jq=wv&3 (1024 j).
// rg=0/1 waves with same jq read identical B-fragment lines -> L1 reuse.
// Explicit 1-step register prefetch of {f2 vec, 4 B-frags, bitmask}: load
// issue and use are a full step (~60 VALU + 5 MFMA) apart -> L2 latency
// hidden. No barriers in the main loop. LDS reduce of 4 j-quarter partials
// per row-group, then normalize+ELU+final write. Bit-identical numerics to
// the previous round (same per-row summation grouping).
__global__ __launch_bounds__(512, 4) void attn_kernel(
    const __hip_bfloat16* __restrict__ hThi,   // [256][4096], row c = h*64+d
    const float* __restrict__ f1L, const float* __restrict__ f2L,
    const unsigned* __restrict__ f2enc,
    const unsigned long long* __restrict__ bits64, // [4096][64]
    float* __restrict__ outf, __hip_bfloat16* __restrict__ outhi,
    __hip_bfloat16* __restrict__ outlo)
{
  __shared__ float part[8][16][68];  // [wave][row][64 d + denom @64]; 34.8 KB
  int t = threadIdx.x;
  int wv = t >> 6, lane = t & 63, quad = lane >> 4, col = lane & 15;
  int rg = wv >> 2, jq = wv & 3;
  int it = blockIdx.x, h = blockIdx.y;
  int i0 = it * 32;
  int irow = i0 + rg * 16 + col;     // weight row handled by this lane

  float f2m = fdec(f2enc[h]);
  float f1i = f1L[h * N_NODES + irow];
  float s0 = f1i + f2m;
  float m = fmaxf(s0, 0.2f * s0);    // lrelu monotone -> valid upper-bound shift
  float f1m = f1i - m;               // s' = f1m + fv;  lr-m = max(s', 0.2*s'+cm)
  float cm = -0.8f * m;

  const unsigned short* H =
      reinterpret_cast<const unsigned short*>(hThi) + (size_t)h * 64 * N_NODES;
  const float* f2h = f2L + h * N_NODES;
  const unsigned long long* brow = bits64 + (size_t)irow * 64;

  const unsigned short* Hb0 = H + (size_t)col * N_NODES;
  const unsigned short* Hb1 = Hb0 + (size_t)16 * N_NODES;
  const unsigned short* Hb2 = Hb0 + (size_t)32 * N_NODES;
  const unsigned short* Hb3 = Hb0 + (size_t)48 * N_NODES;

  int qo = quad * 8;
  int jbase = jq * (N_NODES / 4) + qo;  // this wave's j-quarter, quad offset
  int tbi = jq * 16;                    // first 64-bit mask tile of the quarter

  float4v acc[4] = {{0,0,0,0},{0,0,0,0},{0,0,0,0},{0,0,0,0}};
  float4v accl = {0, 0, 0, 0};
  S8U ones;
  ones.u[0] = ones.u[1] = ones.u[2] = ones.u[3] = 0x3F803F80u; // bf16 1.0 x2

  // pipeline registers (next step's data)
  float4v fa_n, fb_n;
  short8 bA_n, bB_n, bC_n, bD_n;

#define LOADP(OFF) do {                                                  \
    const float* fp_ = f2h + (OFF);                                      \
    fa_n = *reinterpret_cast<const float4v*>(fp_);                       \
    fb_n = *reinterpret_cast<const float4v*>(fp_ + 4);                   \
    bA_n = *reinterpret_cast<const short8*>(Hb0 + (OFF));                \
    bB_n = *reinterpret_cast<const short8*>(Hb1 + (OFF));                \
    bC_n = *reinterpret_cast<const short8*>(Hb2 + (OFF));                \
    bD_n = *reinterpret_cast<const short8*>(Hb3 + (OFF));                \
  } while (0)

#define STEP(FA, FB, WB, B0, B1, B2, B3) do {                            \
    float w[8];                                                          \
    _Pragma("unroll")                                                    \
    for (int jj = 0; jj < 8; ++jj) {                                     \
      float fv = (jj < 4) ? (FA)[jj] : (FB)[jj - 4];                     \
      float sp = f1m + fv;                                               \
      float tb_ = __builtin_fmaf(0.2f, sp, cm);                          \
      float lr = fmaxf(sp, tb_);                                         \
      float e = EXP2(lr);                                                \
      w[jj] = ((WB) & (1u << jj)) ? e : 0.0f;                            \
    }                                                                    \
    S8U afr;                                                             \
    _Pragma("unroll")                                                    \
    for (int k2 = 0; k2 < 4; ++k2)                                       \
      afr.u[k2] = __builtin_amdgcn_perm(__float_as_uint(w[2 * k2 + 1]),  \
                                        __float_as_uint(w[2 * k2]),      \
                                        0x07060302u);                    \
    acc[0] = __builtin_amdgcn_mfma_f32_16x16x32_bf16(afr.v, (B0), acc[0], 0, 0, 0); \
    acc[1] = __builtin_amdgcn_mfma_f32_16x16x32_bf16(afr.v, (B1), acc[1], 0, 0, 0); \
    acc[2] = __builtin_amdgcn_mfma_f32_16x16x32_bf16(afr.v, (B2), acc[2], 0, 0, 0); \
    acc[3] = __builtin_amdgcn_mfma_f32_16x16x32_bf16(afr.v, (B3), acc[3], 0, 0, 0); \
    accl   = __builtin_amdgcn_mfma_f32_16x16x32_bf16(afr.v, ones.v, accl, 0, 0, 0); \
  } while (0)

  LOADP(jbase);                         // prologue: step 0
  unsigned long long wq = brow[tbi];

  for (int t2 = 0; t2 < 16; ++t2) {     // 16 x 64-j tiles, 2 steps each
    unsigned wb_e = (unsigned)(wq >> qo);
    unsigned wb_o = (unsigned)((wq >> 32) >> qo);
    if (t2 < 15) wq = brow[tbi + t2 + 1];          // prefetch next mask tile
    // even step: consume pipeline regs, prefetch odd step
    float4v fa = fa_n, fb = fb_n;
    short8 bA = bA_n, bB = bB_n, bC = bC_n, bD = bD_n;
    LOADP(jbase + t2 * 64 + 32);
    STEP(fa, fb, wb_e, bA, bB, bC, bD);
    // odd step: consume, prefetch next even step
    fa = fa_n; fb = fb_n; bA = bA_n; bB = bB_n; bC = bC_n; bD = bD_n;
    if (t2 < 15) LOADP(jbase + t2 * 64 + 64);
    STEP(fa, fb, wb_o, bA, bB, bC, bD);
  }
#undef LOADP
#undef STEP

  // C/D layout: col=lane&15 (d sub-col), row=quad*4+reg (i). Park partials.
#pragma unroll
  for (int db = 0; db < 4; ++db)
#pragma unroll
    for (int r = 0; r < 4; ++r)
      part[wv][quad * 4 + r][db * 16 + col] = acc[db][r];
  if (col == 0) {
#pragma unroll
    for (int r = 0; r < 4; ++r) part[wv][quad * 4 + r][64] = accl[r];
  }
  __syncthreads();

  // 512 threads: t -> (rowset rg2 = t>>8, row = (t>>4)&15, 4 d at (t&15)*4).
  int rg2 = t >> 8, row = (t >> 4) & 15, dd = (t & 15) * 4;
  float4v s = {0, 0, 0, 0};
  float l = 0.f;
#pragma unroll
  for (int q = 0; q < 4; ++q) {
    float4v pv = *reinterpret_cast<const float4v*>(&part[rg2 * 4 + q][row][dd]);
    s += pv;
    l += part[rg2 * 4 + q][row][64];
  }
  float rl = 1.0f / l;
  float o[4];
#pragma unroll
  for (int r = 0; r < 4; ++r) {
    float v = s[r] * rl;
    o[r] = v > 0.f ? v : EXP2(v * LOG2E) - 1.0f;
  }
  size_t oo = (size_t)(i0 + rg2 * 16 + row) * DIMC + h * 64 + dd;
  if (outf) {
    *reinterpret_cast<float4v*>(outf + oo) = {o[0], o[1], o[2], o[3]};
  } else {
    short4v ohv, olv;
#pragma unroll
    for (int r = 0; r < 4; ++r) {
      __hip_bfloat16 hb = __float2bfloat16(o[r]);
      ohv[r] = (short)bf16_bits(hb);
      olv[r] = (short)bf16_bits(__float2bfloat16(o[r] - __bfloat162float(hb)));
    }
    *reinterpret_cast<short4v*>(reinterpret_cast<unsigned short*>(outhi) + oo) = ohv;
    *reinterpret_cast<short4v*>(reinterpret_cast<unsigned short*>(outlo) + oo) = olv;
  }
}

extern "C" void kernel_launch(void* const* d_in, const int* in_sizes, int n_in,
                              void* d_out, int out_size, void* d_ws, size_t ws_size,
                              hipStream_t stream)
{
  // inputs: t, x, adj, W1, a1, W2, a2  (fp32 except adj int32)
  const float* x   = (const float*)d_in[1];
  const int*   adj = (const int*)d_in[2];
  const float* W1  = (const float*)d_in[3];
  const float* a1  = (const float*)d_in[4];
  const float* W2  = (const float*)d_in[5];
  const float* a2  = (const float*)d_in[6];

  char* ws = (char*)d_ws;
  size_t off = 0;
  auto alloc = [&](size_t b) { size_t o = off; off = (off + b + 255) & ~255ULL; return o; };
  size_t o_bits = alloc((size_t)N_NODES * 64 * 8);          // 2 MB bitmask
  size_t o_w1h  = alloc((size_t)DIMC * DIMC * 2);
  size_t o_w1l  = alloc((size_t)DIMC * DIMC * 2);
  size_t o_w2h  = alloc((size_t)DIMC * DIMC * 2);
  size_t o_w2l  = alloc((size_t)DIMC * DIMC * 2);
  size_t o_xh   = alloc((size_t)N_NODES * DIMC * 2);
  size_t o_xl   = alloc((size_t)N_NODES * DIMC * 2);
  size_t o_hA   = alloc((size_t)N_NODES * DIMC * 4);        // h fp32 row-major
  size_t o_hTh  = alloc((size_t)N_NODES * DIMC * 2);        // h^T hi only
  size_t o_x2h  = alloc((size_t)N_NODES * DIMC * 2);
  size_t o_x2l  = alloc((size_t)N_NODES * DIMC * 2);
  size_t o_f1   = alloc((size_t)NHEADS * N_NODES * 4);
  size_t o_f2   = alloc((size_t)NHEADS * N_NODES * 4);
  size_t o_fm   = alloc(256);                               // 2 layers x 4 u32 (encoded max)

  unsigned long long* bits = (unsigned long long*)(ws + o_bits);
  __hip_bfloat16* w1h = (__hip_bfloat16*)(ws + o_w1h);
  __hip_bfloat16* w1l = (__hip_bfloat16*)(ws + o_w1l);
  __hip_bfloat16* w2h = (__hip_bfloat16*)(ws + o_w2h);
  __hip_bfloat16* w2l = (__hip_bfloat16*)(ws + o_w2l);
  __hip_bfloat16* xh  = (__hip_bfloat16*)(ws + o_xh);
  __hip_bfloat16* xl  = (__hip_bfloat16*)(ws + o_xl);
  float*          hA  = (float*)(ws + o_hA);
  __hip_bfloat16* hTh = (__hip_bfloat16*)(ws + o_hTh);
  __hip_bfloat16* x2h = (__hip_bfloat16*)(ws + o_x2h);
  __hip_bfloat16* x2l = (__hip_bfloat16*)(ws + o_x2l);
  float* f1p = (float*)(ws + o_f1);
  float* f2p = (float*)(ws + o_f2);
  unsigned* fme = (unsigned*)(ws + o_fm);

  hipMemsetAsync(ws + o_fm, 0, 64, stream);  // encoded-max init (monotone min)
  pack_adj_kernel<<<N_NODES * 64 / 4, 256, 0, stream>>>(adj, bits);
  transpose_split_kernel<<<dim3(8, 2, 4), 256, 0, stream>>>(W1, w1h, w1l, 256, 64);
  transpose_split_kernel<<<dim3(8, 2, 4), 256, 0, stream>>>(W2, w2h, w2l, 256, 64);
  split_kernel<<<N_NODES * DIMC / 256, 256, 0, stream>>>(x, xh, xl, N_NODES * DIMC);

  auto layer = [&](const __hip_bfloat16* xih, const __hip_bfloat16* xil,
                   const __hip_bfloat16* wth, const __hip_bfloat16* wtl,
                   const float* av, unsigned* fmk, float* outf,
                   __hip_bfloat16* oh, __hip_bfloat16* ol) {
    gemm_kernel<<<dim3(128, 8), 256, 0, stream>>>(xih, xil, wth, wtl, hA, hTh);
    fvec_kernel<<<1024, 256, 0, stream>>>(hA, av, f1p, f2p, fmk);
    attn_kernel<<<dim3(128, 4), 512, 0, stream>>>(hTh, f1p, f2p, fmk, bits,
                                                  outf, oh, ol);
  };

  layer(xh,  xl,  w1h, w1l, a1, fme,     nullptr,        x2h, x2l);
  layer(x2h, x2l, w2h, w2l, a2, fme + 4, (float*)d_out,  nullptr, nullptr);
}

// Round 5
// 265.341 us; speedup vs baseline: 1.2798x; 1.2774x over previous
//
#include <hip/hip_runtime.h>
#include <hip/hip_bf16.h>

#define N_NODES 4096
#define DIMC    256   // H*D, also K of both layer GEMMs
#define NHEADS  4
#define LOG2E   1.44269504f

typedef __attribute__((ext_vector_type(8))) short  short8;
typedef __attribute__((ext_vector_type(4))) short  short4v;
typedef __attribute__((ext_vector_type(4))) float  float4v;

union S8U { short8 v; unsigned int u[4]; };

#if __has_builtin(__builtin_amdgcn_exp2f)
#define EXP2(x) __builtin_amdgcn_exp2f(x)
#else
#define EXP2(x) exp2f(x)
#endif

__device__ inline unsigned short bf16_bits(__hip_bfloat16 b) {
  union { __hip_bfloat16 b; unsigned short u; } cv; cv.b = b; return cv.u;
}

// monotone float<->u32 encode for atomicMax over signed floats
__device__ inline unsigned fenc(float f) {
  unsigned u = __float_as_uint(f);
  return (u & 0x80000000u) ? ~u : (u | 0x80000000u);
}
__device__ inline float fdec(unsigned k) {
  unsigned u = (k & 0x80000000u) ? (k & 0x7FFFFFFFu) : ~k;
  return __uint_as_float(u);
}

// ---------------- adjacency -> bitmask (1 bit per edge) ----------------
__global__ __launch_bounds__(256) void pack_adj_kernel(
    const int* __restrict__ adj, unsigned long long* __restrict__ bits)
{
  int wid  = blockIdx.x * 4 + (threadIdx.x >> 6);
  int lane = threadIdx.x & 63;
  int row  = wid >> 6;
  int w64  = wid & 63;
  int v = adj[(size_t)row * N_NODES + w64 * 64 + lane];
  unsigned long long m = __ballot(v > 0);
  if (lane == 0) bits[row * 64 + w64] = m;
}

// ------------- fp32 -> split bf16 (hi + residual lo), elementwise --------
__global__ __launch_bounds__(256) void split_kernel(
    const float* __restrict__ in, __hip_bfloat16* __restrict__ hi,
    __hip_bfloat16* __restrict__ lo, int n)
{
  int i = blockIdx.x * 256 + threadIdx.x;
  if (i < n) {
    float v = in[i];
    __hip_bfloat16 h = __float2bfloat16(v);
    hi[i] = h;
    lo[i] = __float2bfloat16(v - __bfloat162float(h));
  }
}

// ------- fp32 transpose + split: in[B][R][C] -> outhi(/lo)[B][C][R] ------
// (weights only). grid (R/32, C/32, B), block 256.
__global__ __launch_bounds__(256) void transpose_split_kernel(
    const float* __restrict__ in, __hip_bfloat16* __restrict__ outhi,
    __hip_bfloat16* __restrict__ outlo, int R, int C)
{
  __shared__ float tile[32][33];
  int t = threadIdx.x;
  int r0 = blockIdx.x * 32, c0 = blockIdx.y * 32;
  size_t base = (size_t)blockIdx.z * R * C;
  int tr = t >> 3, tc = (t & 7) * 4;
  const float* ip = in + base;
  float4v v = *reinterpret_cast<const float4v*>(ip + (size_t)(r0 + tr) * C + c0 + tc);
#pragma unroll
  for (int k = 0; k < 4; ++k) tile[tr][tc + k] = v[k];
  __syncthreads();
  short4v oh, ol;
#pragma unroll
  for (int k = 0; k < 4; ++k) {
    float f = tile[tc + k][tr];
    __hip_bfloat16 hb = __float2bfloat16(f);
    __hip_bfloat16 lb = __float2bfloat16(f - __bfloat162float(hb));
    oh[k] = (short)bf16_bits(hb);
    ol[k] = (short)bf16_bits(lb);
  }
  size_t oidx = base + (size_t)(c0 + tr) * R + r0 + tc;
  *reinterpret_cast<short4v*>(reinterpret_cast<unsigned short*>(outhi) + oidx) = oh;
  if (outlo)
    *reinterpret_cast<short4v*>(reinterpret_cast<unsigned short*>(outlo) + oidx) = ol;
}

// ------- h GEMM (split-bf16) + fused MFMA-fragment-pack epilogue ---------
// out[n][c] fp32 row-major AND Bpack (V in MFMA B-fragment order):
//   u16 index ((h*128 + jt)*4 + db)*512 + lane*8 + jj  holds
//   V[j = jt*32 + (lane>>4)*8 + jj][d = db*16 + (lane&15)]  for head h.
// A wave's B-fragment load in attn is then ONE contiguous 1-KB dwordx4.
// grid (128,8), block 256 (4 waves, 16x16 sub-tiles). blockIdx.x == jt.
__global__ __launch_bounds__(256) void gemm_kernel(
    const __hip_bfloat16* __restrict__ Xhi, const __hip_bfloat16* __restrict__ Xlo,
    const __hip_bfloat16* __restrict__ WThi, const __hip_bfloat16* __restrict__ WTlo,
    float* __restrict__ out, unsigned short* __restrict__ Bpack)
{
  __shared__ float tl[32][33];
  int t = threadIdx.x;
  int wv = t >> 6, lane = t & 63, quad = lane >> 4, col = lane & 15;
  int br = blockIdx.x * 32, bc = blockIdx.y * 32;
  int r0 = br + (wv >> 1) * 16;
  int c0 = bc + (wv & 1) * 16;
  float4v acc = {0, 0, 0, 0};
  const unsigned short* Xh = reinterpret_cast<const unsigned short*>(Xhi);
  const unsigned short* Xl = reinterpret_cast<const unsigned short*>(Xlo);
  const unsigned short* Wh = reinterpret_cast<const unsigned short*>(WThi);
  const unsigned short* Wl = reinterpret_cast<const unsigned short*>(WTlo);
#pragma unroll
  for (int k0 = 0; k0 < DIMC; k0 += 32) {
    size_t ao = (size_t)(r0 + col) * DIMC + k0 + quad * 8;
    size_t bo = (size_t)(c0 + col) * DIMC + k0 + quad * 8;
    short8 ah = *reinterpret_cast<const short8*>(Xh + ao);
    short8 al = *reinterpret_cast<const short8*>(Xl + ao);
    short8 bh = *reinterpret_cast<const short8*>(Wh + bo);
    short8 bl = *reinterpret_cast<const short8*>(Wl + bo);
    acc = __builtin_amdgcn_mfma_f32_16x16x32_bf16(ah, bh, acc, 0, 0, 0);
    acc = __builtin_amdgcn_mfma_f32_16x16x32_bf16(ah, bl, acc, 0, 0, 0);
    acc = __builtin_amdgcn_mfma_f32_16x16x32_bf16(al, bh, acc, 0, 0, 0);
  }
  int lr = (wv >> 1) * 16 + quad * 4, lc = (wv & 1) * 16 + col;
#pragma unroll
  for (int r = 0; r < 4; ++r) {
    out[(size_t)(r0 + quad * 4 + r) * DIMC + c0 + col] = acc[r];
    tl[lr + r][lc] = acc[r];     // tl[local_j][local_c]
  }
  __syncthreads();
  int tr = t >> 3, tc = (t & 7) * 4;   // tr: local c, tc: local j (4-wide)
  short4v oh;
#pragma unroll
  for (int k = 0; k < 4; ++k)
    oh[k] = (short)bf16_bits(__float2bfloat16(tl[tc + k][tr]));
  int c = bc + tr;
  int h = c >> 6, d = c & 63, db = d >> 4, colp = d & 15;
  int quadp = tc >> 3, jj = tc & 7;    // jj in {0,4}
  size_t fragu = (((size_t)(h * 128 + blockIdx.x) * 4 + db) * 64
                  + quadp * 16 + colp) * 8 + jj;
  *reinterpret_cast<short4v*>(Bpack + fragu) = oh;
}

// ---- f1/f2 (log2-scaled) + fused per-head global max (encoded atomic) ---
// grid 1024, block 256: wave per node.
__global__ __launch_bounds__(256) void fvec_kernel(
    const float* __restrict__ hA, const float* __restrict__ a,
    float* __restrict__ f1L, float* __restrict__ f2L,
    unsigned* __restrict__ f2enc)
{
  __shared__ float bm[4][4];  // [wave][head]
  int t = threadIdx.x, wv = t >> 6, lane = t & 63;
  int n = blockIdx.x * 4 + wv;
  int h = lane >> 4, d4 = (lane & 15) * 4;
  float4v v = *reinterpret_cast<const float4v*>(hA + (size_t)n * DIMC + lane * 4);
  const float* ah = a + h * 128;
  float s1 = v[0]*ah[d4] + v[1]*ah[d4+1] + v[2]*ah[d4+2] + v[3]*ah[d4+3];
  float s2 = v[0]*ah[64+d4] + v[1]*ah[64+d4+1] + v[2]*ah[64+d4+2] + v[3]*ah[64+d4+3];
#pragma unroll
  for (int o = 8; o >= 1; o >>= 1) {
    s1 += __shfl_xor(s1, o);
    s2 += __shfl_xor(s2, o);
  }
  float s2s = s2 * LOG2E;
  if ((lane & 15) == 0) {
    f1L[h * N_NODES + n] = s1 * LOG2E;
    f2L[h * N_NODES + n] = s2s;
    bm[wv][h] = s2s;
  }
  __syncthreads();
  if (t < 4) {
    float m = fmaxf(fmaxf(bm[0][t], bm[1][t]), fmaxf(bm[2][t], bm[3][t]));
    atomicMax(f2enc + t, fenc(m));
  }
}

// ------ fused masked-softmax attention, fragment-packed streaming --------
// grid (256, 4) = (16-row i-tile, head). block 512 = 8 waves; wave wv sweeps
// the disjoint j-range [wv*512, (wv+1)*512) for the SAME 16 i-rows.
// 1024 blocks = 4 blocks/CU x 8 waves = 32 waves/CU (100% occupancy).
// B-operands come from Bpack: each (32-j, db) fragment is ONE contiguous
// 1-KB coalesced dwordx4 load (4 KB streaming per step) - no row scatter,
// no LDS, no barriers in the main loop. LDS reduce of the 8 j-partials,
// then normalize + ELU + final write.
__global__ __launch_bounds__(512, 8) void attn_kernel(
    const unsigned short* __restrict__ Bpack,
    const float* __restrict__ f1L, const float* __restrict__ f2L,
    const unsigned* __restrict__ f2enc,
    const unsigned long long* __restrict__ bits64, // [4096][64]
    float* __restrict__ outf, __hip_bfloat16* __restrict__ outhi,
    __hip_bfloat16* __restrict__ outlo)
{
  __shared__ float part[8][16][68];  // [wave][row][64 d + denom @64]; 34.8 KB
  int t = threadIdx.x;
  int wv = t >> 6, lane = t & 63, quad = lane >> 4, col = lane & 15;
  int it = blockIdx.x, h = blockIdx.y;
  int i0 = it * 16;
  int irow = i0 + col;               // weight row handled by this lane

  float f2m = fdec(f2enc[h]);
  float f1i = f1L[h * N_NODES + irow];
  float s0 = f1i + f2m;
  float m = fmaxf(s0, 0.2f * s0);    // lrelu monotone -> valid upper-bound shift
  float f1m = f1i - m;               // s' = f1m + fv;  lr-m = max(s', 0.2*s'+cm)
  float cm = -0.8f * m;

  const float* f2h = f2L + h * N_NODES;
  const unsigned long long* brow = bits64 + (size_t)irow * 64;
  // wave's fragment stream: 16 steps x 4 db x 512 u16, contiguous
  const unsigned short* bp =
      Bpack + ((size_t)(h * 128 + wv * 16)) * 4 * 512 + lane * 8;
  int jbase = wv * 512;

  float4v acc[4] = {{0,0,0,0},{0,0,0,0},{0,0,0,0},{0,0,0,0}};
  float4v accl = {0, 0, 0, 0};
  S8U ones;
  ones.u[0] = ones.u[1] = ones.u[2] = ones.u[3] = 0x3F803F80u; // bf16 1.0 x2

  for (int s = 0; s < 16; ++s) {     // 16 x 32-j steps, no barriers
    int j0 = jbase + s * 32;
    unsigned wb = (unsigned)(brow[j0 >> 6] >> ((j0 & 32) | (quad * 8)));
    const float* fp = f2h + j0 + quad * 8;
    float4v fa = *reinterpret_cast<const float4v*>(fp);
    float4v fb = *reinterpret_cast<const float4v*>(fp + 4);
    const unsigned short* bs = bp + (size_t)s * 2048;
    short8 b0 = *reinterpret_cast<const short8*>(bs);
    short8 b1 = *reinterpret_cast<const short8*>(bs + 512);
    short8 b2 = *reinterpret_cast<const short8*>(bs + 1024);
    short8 b3 = *reinterpret_cast<const short8*>(bs + 1536);
    float w[8];
#pragma unroll
    for (int jj = 0; jj < 8; ++jj) {
      float fv = (jj < 4) ? fa[jj] : fb[jj - 4];
      float sp = f1m + fv;
      float tb = __builtin_fmaf(0.2f, sp, cm);
      float lr = fmaxf(sp, tb);
      float e = EXP2(lr);
      w[jj] = (wb & (1u << jj)) ? e : 0.0f;
    }
    S8U afr;
#pragma unroll
    for (int k2 = 0; k2 < 4; ++k2)   // truncate-pack two fp32 -> bf16x2
      afr.u[k2] = __builtin_amdgcn_perm(__float_as_uint(w[2 * k2 + 1]),
                                        __float_as_uint(w[2 * k2]),
                                        0x07060302u);
    acc[0] = __builtin_amdgcn_mfma_f32_16x16x32_bf16(afr.v, b0, acc[0], 0, 0, 0);
    acc[1] = __builtin_amdgcn_mfma_f32_16x16x32_bf16(afr.v, b1, acc[1], 0, 0, 0);
    acc[2] = __builtin_amdgcn_mfma_f32_16x16x32_bf16(afr.v, b2, acc[2], 0, 0, 0);
    acc[3] = __builtin_amdgcn_mfma_f32_16x16x32_bf16(afr.v, b3, acc[3], 0, 0, 0);
    accl   = __builtin_amdgcn_mfma_f32_16x16x32_bf16(afr.v, ones.v, accl, 0, 0, 0);
  }

  // C/D layout: col=lane&15 (d sub-col), row=quad*4+reg (i). Park partials.
#pragma unroll
  for (int db = 0; db < 4; ++db)
#pragma unroll
    for (int r = 0; r < 4; ++r)
      part[wv][quad * 4 + r][db * 16 + col] = acc[db][r];
  if (col == 0) {
#pragma unroll
    for (int r = 0; r < 4; ++r) part[wv][quad * 4 + r][64] = accl[r];
  }
  __syncthreads();

  // 256 active threads: t -> (row = t>>4, 4 d at (t&15)*4). Sum 8 partials.
  if (t < 256) {
    int row = t >> 4, dd = (t & 15) * 4;
    float4v s = {0, 0, 0, 0};
    float l = 0.f;
#pragma unroll
    for (int w2 = 0; w2 < 8; ++w2) {
      float4v pv = *reinterpret_cast<const float4v*>(&part[w2][row][dd]);
      s += pv;
      l += part[w2][row][64];
    }
    float rl = 1.0f / l;
    float o[4];
#pragma unroll
    for (int r = 0; r < 4; ++r) {
      float v = s[r] * rl;
      o[r] = v > 0.f ? v : EXP2(v * LOG2E) - 1.0f;
    }
    size_t oo = (size_t)(i0 + row) * DIMC + h * 64 + dd;
    if (outf) {
      *reinterpret_cast<float4v*>(outf + oo) = {o[0], o[1], o[2], o[3]};
    } else {
      short4v ohv, olv;
#pragma unroll
      for (int r = 0; r < 4; ++r) {
        __hip_bfloat16 hb = __float2bfloat16(o[r]);
        ohv[r] = (short)bf16_bits(hb);
        olv[r] = (short)bf16_bits(__float2bfloat16(o[r] - __bfloat162float(hb)));
      }
      *reinterpret_cast<short4v*>(reinterpret_cast<unsigned short*>(outhi) + oo) = ohv;
      *reinterpret_cast<short4v*>(reinterpret_cast<unsigned short*>(outlo) + oo) = olv;
    }
  }
}

extern "C" void kernel_launch(void* const* d_in, const int* in_sizes, int n_in,
                              void* d_out, int out_size, void* d_ws, size_t ws_size,
                              hipStream_t stream)
{
  // inputs: t, x, adj, W1, a1, W2, a2  (fp32 except adj int32)
  const float* x   = (const float*)d_in[1];
  const int*   adj = (const int*)d_in[2];
  const float* W1  = (const float*)d_in[3];
  const float* a1  = (const float*)d_in[4];
  const float* W2  = (const float*)d_in[5];
  const float* a2  = (const float*)d_in[6];

  char* ws = (char*)d_ws;
  size_t off = 0;
  auto alloc = [&](size_t b) { size_t o = off; off = (off + b + 255) & ~255ULL; return o; };
  size_t o_bits = alloc((size_t)N_NODES * 64 * 8);          // 2 MB bitmask
  size_t o_w1h  = alloc((size_t)DIMC * DIMC * 2);
  size_t o_w1l  = alloc((size_t)DIMC * DIMC * 2);
  size_t o_w2h  = alloc((size_t)DIMC * DIMC * 2);
  size_t o_w2l  = alloc((size_t)DIMC * DIMC * 2);
  size_t o_xh   = alloc((size_t)N_NODES * DIMC * 2);
  size_t o_xl   = alloc((size_t)N_NODES * DIMC * 2);
  size_t o_hA   = alloc((size_t)N_NODES * DIMC * 4);        // h fp32 row-major
  size_t o_bp   = alloc((size_t)N_NODES * DIMC * 2);        // Bpack (2 MB)
  size_t o_x2h  = alloc((size_t)N_NODES * DIMC * 2);
  size_t o_x2l  = alloc((size_t)N_NODES * DIMC * 2);
  size_t o_f1   = alloc((size_t)NHEADS * N_NODES * 4);
  size_t o_f2   = alloc((size_t)NHEADS * N_NODES * 4);
  size_t o_fm   = alloc(256);                               // 2 layers x 4 u32 (encoded max)

  unsigned long long* bits = (unsigned long long*)(ws + o_bits);
  __hip_bfloat16* w1h = (__hip_bfloat16*)(ws + o_w1h);
  __hip_bfloat16* w1l = (__hip_bfloat16*)(ws + o_w1l);
  __hip_bfloat16* w2h = (__hip_bfloat16*)(ws + o_w2h);
  __hip_bfloat16* w2l = (__hip_bfloat16*)(ws + o_w2l);
  __hip_bfloat16* xh  = (__hip_bfloat16*)(ws + o_xh);
  __hip_bfloat16* xl  = (__hip_bfloat16*)(ws + o_xl);
  float*          hA  = (float*)(ws + o_hA);
  unsigned short* bpk = (unsigned short*)(ws + o_bp);
  __hip_bfloat16* x2h = (__hip_bfloat16*)(ws + o_x2h);
  __hip_bfloat16* x2l = (__hip_bfloat16*)(ws + o_x2l);
  float* f1p = (float*)(ws + o_f1);
  float* f2p = (float*)(ws + o_f2);
  unsigned* fme = (unsigned*)(ws + o_fm);

  hipMemsetAsync(ws + o_fm, 0, 64, stream);  // encoded-max init (monotone min)
  pack_adj_kernel<<<N_NODES * 64 / 4, 256, 0, stream>>>(adj, bits);
  transpose_split_kernel<<<dim3(8, 2, 4), 256, 0, stream>>>(W1, w1h, w1l, 256, 64);
  transpose_split_kernel<<<dim3(8, 2, 4), 256, 0, stream>>>(W2, w2h, w2l, 256, 64);
  split_kernel<<<N_NODES * DIMC / 256, 256, 0, stream>>>(x, xh, xl, N_NODES * DIMC);

  auto layer = [&](const __hip_bfloat16* xih, const __hip_bfloat16* xil,
                   const __hip_bfloat16* wth, const __hip_bfloat16* wtl,
                   const float* av, unsigned* fmk, float* outf,
                   __hip_bfloat16* oh, __hip_bfloat16* ol) {
    gemm_kernel<<<dim3(128, 8), 256, 0, stream>>>(xih, xil, wth, wtl, hA, bpk);
    fvec_kernel<<<1024, 256, 0, stream>>>(hA, av, f1p, f2p, fmk);
    attn_kernel<<<dim3(256, 4), 512, 0, stream>>>(bpk, f1p, f2p, fmk, bits,
                                                  outf, oh, ol);
  };

  layer(xh,  xl,  w1h, w1l, a1, fme,     nullptr,        x2h, x2l);
  layer(x2h, x2l, w2h, w2l, a2, fme + 4, (float*)d_out,  nullptr, nullptr);
}

// Round 6
// 250.749 us; speedup vs baseline: 1.3543x; 1.0582x over previous
//
#include <hip/hip_runtime.h>
#include <hip/hip_bf16.h>

#define N_NODES 4096
#define DIMC    256   // H*D, also K of both layer GEMMs
#define NHEADS  4
#define LOG2E   1.44269504f

typedef __attribute__((ext_vector_type(8))) short  short8;
typedef __attribute__((ext_vector_type(4))) short  short4v;
typedef __attribute__((ext_vector_type(4))) float  float4v;

union S8U { short8 v; unsigned int u[4]; };

#if __has_builtin(__builtin_amdgcn_exp2f)
#define EXP2(x) __builtin_amdgcn_exp2f(x)
#else
#define EXP2(x) exp2f(x)
#endif

__device__ inline unsigned short bf16_bits(__hip_bfloat16 b) {
  union { __hip_bfloat16 b; unsigned short u; } cv; cv.b = b; return cv.u;
}

// monotone float<->u32 encode for atomicMax over signed floats
__device__ inline unsigned fenc(float f) {
  unsigned u = __float_as_uint(f);
  return (u & 0x80000000u) ? ~u : (u | 0x80000000u);
}
__device__ inline float fdec(unsigned k) {
  unsigned u = (k & 0x80000000u) ? (k & 0x7FFFFFFFu) : ~k;
  return __uint_as_float(u);
}

// ---------------- adjacency -> bitmask (1 bit per edge) ----------------
__global__ __launch_bounds__(256) void pack_adj_kernel(
    const int* __restrict__ adj, unsigned long long* __restrict__ bits)
{
  int wid  = blockIdx.x * 4 + (threadIdx.x >> 6);
  int lane = threadIdx.x & 63;
  int row  = wid >> 6;
  int w64  = wid & 63;
  int v = adj[(size_t)row * N_NODES + w64 * 64 + lane];
  unsigned long long m = __ballot(v > 0);
  if (lane == 0) bits[row * 64 + w64] = m;
}

// ------------- fp32 -> split bf16 (hi + residual lo), elementwise --------
__global__ __launch_bounds__(256) void split_kernel(
    const float* __restrict__ in, __hip_bfloat16* __restrict__ hi,
    __hip_bfloat16* __restrict__ lo, int n)
{
  int i = blockIdx.x * 256 + threadIdx.x;
  if (i < n) {
    float v = in[i];
    __hip_bfloat16 h = __float2bfloat16(v);
    hi[i] = h;
    lo[i] = __float2bfloat16(v - __bfloat162float(h));
  }
}

// ------- fp32 transpose + split: in[B][R][C] -> outhi(/lo)[B][C][R] ------
// (weights only). grid (R/32, C/32, B), block 256.
__global__ __launch_bounds__(256) void transpose_split_kernel(
    const float* __restrict__ in, __hip_bfloat16* __restrict__ outhi,
    __hip_bfloat16* __restrict__ outlo, int R, int C)
{
  __shared__ float tile[32][33];
  int t = threadIdx.x;
  int r0 = blockIdx.x * 32, c0 = blockIdx.y * 32;
  size_t base = (size_t)blockIdx.z * R * C;
  int tr = t >> 3, tc = (t & 7) * 4;
  const float* ip = in + base;
  float4v v = *reinterpret_cast<const float4v*>(ip + (size_t)(r0 + tr) * C + c0 + tc);
#pragma unroll
  for (int k = 0; k < 4; ++k) tile[tr][tc + k] = v[k];
  __syncthreads();
  short4v oh, ol;
#pragma unroll
  for (int k = 0; k < 4; ++k) {
    float f = tile[tc + k][tr];
    __hip_bfloat16 hb = __float2bfloat16(f);
    __hip_bfloat16 lb = __float2bfloat16(f - __bfloat162float(hb));
    oh[k] = (short)bf16_bits(hb);
    ol[k] = (short)bf16_bits(lb);
  }
  size_t oidx = base + (size_t)(c0 + tr) * R + r0 + tc;
  *reinterpret_cast<short4v*>(reinterpret_cast<unsigned short*>(outhi) + oidx) = oh;
  if (outlo)
    *reinterpret_cast<short4v*>(reinterpret_cast<unsigned short*>(outlo) + oidx) = ol;
}

// ------- h GEMM (split-bf16) + fused MFMA-fragment-pack epilogue ---------
// out[n][c] fp32 row-major AND Bpack (V in MFMA B-fragment order):
//   u16 index ((h*128 + jt)*4 + db)*512 + lane*8 + jj  holds
//   V[j = jt*32 + (lane>>4)*8 + jj][d = db*16 + (lane&15)]  for head h.
// A wave's B-fragment load in attn is then ONE contiguous 1-KB dwordx4.
// grid (128,8), block 256 (4 waves, 16x16 sub-tiles). blockIdx.x == jt.
__global__ __launch_bounds__(256) void gemm_kernel(
    const __hip_bfloat16* __restrict__ Xhi, const __hip_bfloat16* __restrict__ Xlo,
    const __hip_bfloat16* __restrict__ WThi, const __hip_bfloat16* __restrict__ WTlo,
    float* __restrict__ out, unsigned short* __restrict__ Bpack)
{
  __shared__ float tl[32][33];
  int t = threadIdx.x;
  int wv = t >> 6, lane = t & 63, quad = lane >> 4, col = lane & 15;
  int br = blockIdx.x * 32, bc = blockIdx.y * 32;
  int r0 = br + (wv >> 1) * 16;
  int c0 = bc + (wv & 1) * 16;
  float4v acc = {0, 0, 0, 0};
  const unsigned short* Xh = reinterpret_cast<const unsigned short*>(Xhi);
  const unsigned short* Xl = reinterpret_cast<const unsigned short*>(Xlo);
  const unsigned short* Wh = reinterpret_cast<const unsigned short*>(WThi);
  const unsigned short* Wl = reinterpret_cast<const unsigned short*>(WTlo);
#pragma unroll
  for (int k0 = 0; k0 < DIMC; k0 += 32) {
    size_t ao = (size_t)(r0 + col) * DIMC + k0 + quad * 8;
    size_t bo = (size_t)(c0 + col) * DIMC + k0 + quad * 8;
    short8 ah = *reinterpret_cast<const short8*>(Xh + ao);
    short8 al = *reinterpret_cast<const short8*>(Xl + ao);
    short8 bh = *reinterpret_cast<const short8*>(Wh + bo);
    short8 bl = *reinterpret_cast<const short8*>(Wl + bo);
    acc = __builtin_amdgcn_mfma_f32_16x16x32_bf16(ah, bh, acc, 0, 0, 0);
    acc = __builtin_amdgcn_mfma_f32_16x16x32_bf16(ah, bl, acc, 0, 0, 0);
    acc = __builtin_amdgcn_mfma_f32_16x16x32_bf16(al, bh, acc, 0, 0, 0);
  }
  int lr = (wv >> 1) * 16 + quad * 4, lc = (wv & 1) * 16 + col;
#pragma unroll
  for (int r = 0; r < 4; ++r) {
    out[(size_t)(r0 + quad * 4 + r) * DIMC + c0 + col] = acc[r];
    tl[lr + r][lc] = acc[r];     // tl[local_j][local_c]
  }
  __syncthreads();
  int tr = t >> 3, tc = (t & 7) * 4;   // tr: local c, tc: local j (4-wide)
  short4v oh;
#pragma unroll
  for (int k = 0; k < 4; ++k)
    oh[k] = (short)bf16_bits(__float2bfloat16(tl[tc + k][tr]));
  int c = bc + tr;
  int h = c >> 6, d = c & 63, db = d >> 4, colp = d & 15;
  int quadp = tc >> 3, jj = tc & 7;    // jj in {0,4}
  size_t fragu = (((size_t)(h * 128 + blockIdx.x) * 4 + db) * 64
                  + quadp * 16 + colp) * 8 + jj;
  *reinterpret_cast<short4v*>(Bpack + fragu) = oh;
}

// ---- f1/f2 (log2-scaled) + fused per-head global max (encoded atomic) ---
// grid 1024, block 256: wave per node.
__global__ __launch_bounds__(256) void fvec_kernel(
    const float* __restrict__ hA, const float* __restrict__ a,
    float* __restrict__ f1L, float* __restrict__ f2L,
    unsigned* __restrict__ f2enc)
{
  __shared__ float bm[4][4];  // [wave][head]
  int t = threadIdx.x, wv = t >> 6, lane = t & 63;
  int n = blockIdx.x * 4 + wv;
  int h = lane >> 4, d4 = (lane & 15) * 4;
  float4v v = *reinterpret_cast<const float4v*>(hA + (size_t)n * DIMC + lane * 4);
  const float* ah = a + h * 128;
  float s1 = v[0]*ah[d4] + v[1]*ah[d4+1] + v[2]*ah[d4+2] + v[3]*ah[d4+3];
  float s2 = v[0]*ah[64+d4] + v[1]*ah[64+d4+1] + v[2]*ah[64+d4+2] + v[3]*ah[64+d4+3];
#pragma unroll
  for (int o = 8; o >= 1; o >>= 1) {
    s1 += __shfl_xor(s1, o);
    s2 += __shfl_xor(s2, o);
  }
  float s2s = s2 * LOG2E;
  if ((lane & 15) == 0) {
    f1L[h * N_NODES + n] = s1 * LOG2E;
    f2L[h * N_NODES + n] = s2s;
    bm[wv][h] = s2s;
  }
  __syncthreads();
  if (t < 4) {
    float m = fmaxf(fmaxf(bm[0][t], bm[1][t]), fmaxf(bm[2][t], bm[3][t]));
    atomicMax(f2enc + t, fenc(m));
  }
}

// ------ fused masked-softmax attention, fragment-packed streaming --------
// grid (128, 4) = (32-row i-tile, head). block 512 = 8 waves; wave wv sweeps
// the disjoint j-range [wv*512, (wv+1)*512) for the SAME 32 i-rows, keeping
// TWO A-fragments (rows i0..15 and i0+16..31) against each B-fragment:
// 10 MFMA per 4-KB B-load (2x arithmetic intensity vs 16-row tiles) and
// half the total Bpack L2 traffic. __launch_bounds__(512, 4): VGPR cap 128
// so the compiler can batch a whole step's loads before one wait (round-4's
// (512,8)->32 VGPR forced 4 serialized L2 round-trips per step = 815 cy/step).
// 512 blocks = 2 blocks/CU (LDS 69.6 KB each) = 4 waves/SIMD; latency is
// covered by ILP within the step. No barriers in the main loop. LDS reduce
// of the 8 j-partials, then normalize + ELU + final write.
// Summation tree per row identical to round 4 (8 partials of 512 j).
__global__ __launch_bounds__(512, 4) void attn_kernel(
    const unsigned short* __restrict__ Bpack,
    const float* __restrict__ f1L, const float* __restrict__ f2L,
    const unsigned* __restrict__ f2enc,
    const unsigned long long* __restrict__ bits64, // [4096][64]
    float* __restrict__ outf, __hip_bfloat16* __restrict__ outhi,
    __hip_bfloat16* __restrict__ outlo)
{
  __shared__ float part[8][32][68];  // [wave][row][64 d + denom @64]; 69.6 KB
  int t = threadIdx.x;
  int wv = t >> 6, lane = t & 63, quad = lane >> 4, col = lane & 15;
  int it = blockIdx.x, h = blockIdx.y;
  int i0 = it * 32;
  int irow0 = i0 + col;              // rows for A-fragment 0
  int irow1 = i0 + 16 + col;         // rows for A-fragment 1

  float f2m = fdec(f2enc[h]);
  float f1i0 = f1L[h * N_NODES + irow0];
  float f1i1 = f1L[h * N_NODES + irow1];
  float s00 = f1i0 + f2m;
  float m0 = fmaxf(s00, 0.2f * s00); // lrelu monotone -> valid upper-bound shift
  float f1m0 = f1i0 - m0;
  float cm0 = -0.8f * m0;
  float s01 = f1i1 + f2m;
  float m1 = fmaxf(s01, 0.2f * s01);
  float f1m1 = f1i1 - m1;
  float cm1 = -0.8f * m1;

  const float* f2h = f2L + h * N_NODES;
  const unsigned long long* brow0 = bits64 + (size_t)irow0 * 64;
  const unsigned long long* brow1 = bits64 + (size_t)irow1 * 64;
  // wave's fragment stream: 16 steps x 4 db x 512 u16, contiguous
  const unsigned short* bp =
      Bpack + ((size_t)(h * 128 + wv * 16)) * 4 * 512 + lane * 8;
  int jbase = wv * 512;

  float4v acc0[4] = {{0,0,0,0},{0,0,0,0},{0,0,0,0},{0,0,0,0}};
  float4v acc1[4] = {{0,0,0,0},{0,0,0,0},{0,0,0,0},{0,0,0,0}};
  float4v accl0 = {0, 0, 0, 0}, accl1 = {0, 0, 0, 0};
  S8U ones;
  ones.u[0] = ones.u[1] = ones.u[2] = ones.u[3] = 0x3F803F80u; // bf16 1.0 x2

  for (int s = 0; s < 16; ++s) {     // 16 x 32-j steps, no barriers
    int j0 = jbase + s * 32;
    int sh = (j0 & 32) | (quad * 8);
    unsigned wb0 = (unsigned)(brow0[j0 >> 6] >> sh);
    unsigned wb1 = (unsigned)(brow1[j0 >> 6] >> sh);
    const float* fp = f2h + j0 + quad * 8;
    float4v fa = *reinterpret_cast<const float4v*>(fp);
    float4v fb = *reinterpret_cast<const float4v*>(fp + 4);
    const unsigned short* bs = bp + (size_t)s * 2048;
    short8 b0 = *reinterpret_cast<const short8*>(bs);
    short8 b1 = *reinterpret_cast<const short8*>(bs + 512);
    short8 b2 = *reinterpret_cast<const short8*>(bs + 1024);
    short8 b3 = *reinterpret_cast<const short8*>(bs + 1536);
    float w0[8], w1[8];
#pragma unroll
    for (int jj = 0; jj < 8; ++jj) {
      float fv = (jj < 4) ? fa[jj] : fb[jj - 4];
      float sp0 = f1m0 + fv;
      float tb0 = __builtin_fmaf(0.2f, sp0, cm0);
      float e0 = EXP2(fmaxf(sp0, tb0));
      w0[jj] = (wb0 & (1u << jj)) ? e0 : 0.0f;
      float sp1 = f1m1 + fv;
      float tb1 = __builtin_fmaf(0.2f, sp1, cm1);
      float e1 = EXP2(fmaxf(sp1, tb1));
      w1[jj] = (wb1 & (1u << jj)) ? e1 : 0.0f;
    }
    S8U afr0, afr1;
#pragma unroll
    for (int k2 = 0; k2 < 4; ++k2) { // truncate-pack two fp32 -> bf16x2
      afr0.u[k2] = __builtin_amdgcn_perm(__float_as_uint(w0[2 * k2 + 1]),
                                         __float_as_uint(w0[2 * k2]),
                                         0x07060302u);
      afr1.u[k2] = __builtin_amdgcn_perm(__float_as_uint(w1[2 * k2 + 1]),
                                         __float_as_uint(w1[2 * k2]),
                                         0x07060302u);
    }
    acc0[0] = __builtin_amdgcn_mfma_f32_16x16x32_bf16(afr0.v, b0, acc0[0], 0, 0, 0);
    acc0[1] = __builtin_amdgcn_mfma_f32_16x16x32_bf16(afr0.v, b1, acc0[1], 0, 0, 0);
    acc0[2] = __builtin_amdgcn_mfma_f32_16x16x32_bf16(afr0.v, b2, acc0[2], 0, 0, 0);
    acc0[3] = __builtin_amdgcn_mfma_f32_16x16x32_bf16(afr0.v, b3, acc0[3], 0, 0, 0);
    accl0   = __builtin_amdgcn_mfma_f32_16x16x32_bf16(afr0.v, ones.v, accl0, 0, 0, 0);
    acc1[0] = __builtin_amdgcn_mfma_f32_16x16x32_bf16(afr1.v, b0, acc1[0], 0, 0, 0);
    acc1[1] = __builtin_amdgcn_mfma_f32_16x16x32_bf16(afr1.v, b1, acc1[1], 0, 0, 0);
    acc1[2] = __builtin_amdgcn_mfma_f32_16x16x32_bf16(afr1.v, b2, acc1[2], 0, 0, 0);
    acc1[3] = __builtin_amdgcn_mfma_f32_16x16x32_bf16(afr1.v, b3, acc1[3], 0, 0, 0);
    accl1   = __builtin_amdgcn_mfma_f32_16x16x32_bf16(afr1.v, ones.v, accl1, 0, 0, 0);
  }

  // C/D layout: col=lane&15 (d sub-col), row=quad*4+reg (i). Park partials.
#pragma unroll
  for (int db = 0; db < 4; ++db)
#pragma unroll
    for (int r = 0; r < 4; ++r) {
      part[wv][quad * 4 + r][db * 16 + col] = acc0[db][r];
      part[wv][16 + quad * 4 + r][db * 16 + col] = acc1[db][r];
    }
  if (col == 0) {
#pragma unroll
    for (int r = 0; r < 4; ++r) {
      part[wv][quad * 4 + r][64] = accl0[r];
      part[wv][16 + quad * 4 + r][64] = accl1[r];
    }
  }
  __syncthreads();

  // 512 threads: t -> (row = t>>4 in 0..31, 4 d at (t&15)*4). Sum 8 partials.
  int row = t >> 4, dd = (t & 15) * 4;
  float4v s = {0, 0, 0, 0};
  float l = 0.f;
#pragma unroll
  for (int w2 = 0; w2 < 8; ++w2) {
    float4v pv = *reinterpret_cast<const float4v*>(&part[w2][row][dd]);
    s += pv;
    l += part[w2][row][64];
  }
  float rl = 1.0f / l;
  float o[4];
#pragma unroll
  for (int r = 0; r < 4; ++r) {
    float v = s[r] * rl;
    o[r] = v > 0.f ? v : EXP2(v * LOG2E) - 1.0f;
  }
  size_t oo = (size_t)(i0 + row) * DIMC + h * 64 + dd;
  if (outf) {
    *reinterpret_cast<float4v*>(outf + oo) = {o[0], o[1], o[2], o[3]};
  } else {
    short4v ohv, olv;
#pragma unroll
    for (int r = 0; r < 4; ++r) {
      __hip_bfloat16 hb = __float2bfloat16(o[r]);
      ohv[r] = (short)bf16_bits(hb);
      olv[r] = (short)bf16_bits(__float2bfloat16(o[r] - __bfloat162float(hb)));
    }
    *reinterpret_cast<short4v*>(reinterpret_cast<unsigned short*>(outhi) + oo) = ohv;
    *reinterpret_cast<short4v*>(reinterpret_cast<unsigned short*>(outlo) + oo) = olv;
  }
}

extern "C" void kernel_launch(void* const* d_in, const int* in_sizes, int n_in,
                              void* d_out, int out_size, void* d_ws, size_t ws_size,
                              hipStream_t stream)
{
  // inputs: t, x, adj, W1, a1, W2, a2  (fp32 except adj int32)
  const float* x   = (const float*)d_in[1];
  const int*   adj = (const int*)d_in[2];
  const float* W1  = (const float*)d_in[3];
  const float* a1  = (const float*)d_in[4];
  const float* W2  = (const float*)d_in[5];
  const float* a2  = (const float*)d_in[6];

  char* ws = (char*)d_ws;
  size_t off = 0;
  auto alloc = [&](size_t b) { size_t o = off; off = (off + b + 255) & ~255ULL; return o; };
  size_t o_bits = alloc((size_t)N_NODES * 64 * 8);          // 2 MB bitmask
  size_t o_w1h  = alloc((size_t)DIMC * DIMC * 2);
  size_t o_w1l  = alloc((size_t)DIMC * DIMC * 2);
  size_t o_w2h  = alloc((size_t)DIMC * DIMC * 2);
  size_t o_w2l  = alloc((size_t)DIMC * DIMC * 2);
  size_t o_xh   = alloc((size_t)N_NODES * DIMC * 2);
  size_t o_xl   = alloc((size_t)N_NODES * DIMC * 2);
  size_t o_hA   = alloc((size_t)N_NODES * DIMC * 4);        // h fp32 row-major
  size_t o_bp   = alloc((size_t)N_NODES * DIMC * 2);        // Bpack (2 MB)
  size_t o_x2h  = alloc((size_t)N_NODES * DIMC * 2);
  size_t o_x2l  = alloc((size_t)N_NODES * DIMC * 2);
  size_t o_f1   = alloc((size_t)NHEADS * N_NODES * 4);
  size_t o_f2   = alloc((size_t)NHEADS * N_NODES * 4);
  size_t o_fm   = alloc(256);                               // 2 layers x 4 u32 (encoded max)

  unsigned long long* bits = (unsigned long long*)(ws + o_bits);
  __hip_bfloat16* w1h = (__hip_bfloat16*)(ws + o_w1h);
  __hip_bfloat16* w1l = (__hip_bfloat16*)(ws + o_w1l);
  __hip_bfloat16* w2h = (__hip_bfloat16*)(ws + o_w2h);
  __hip_bfloat16* w2l = (__hip_bfloat16*)(ws + o_w2l);
  __hip_bfloat16* xh  = (__hip_bfloat16*)(ws + o_xh);
  __hip_bfloat16* xl  = (__hip_bfloat16*)(ws + o_xl);
  float*          hA  = (float*)(ws + o_hA);
  unsigned short* bpk = (unsigned short*)(ws + o_bp);
  __hip_bfloat16* x2h = (__hip_bfloat16*)(ws + o_x2h);
  __hip_bfloat16* x2l = (__hip_bfloat16*)(ws + o_x2l);
  float* f1p = (float*)(ws + o_f1);
  float* f2p = (float*)(ws + o_f2);
  unsigned* fme = (unsigned*)(ws + o_fm);

  hipMemsetAsync(ws + o_fm, 0, 64, stream);  // encoded-max init (monotone min)
  pack_adj_kernel<<<N_NODES * 64 / 4, 256, 0, stream>>>(adj, bits);
  transpose_split_kernel<<<dim3(8, 2, 4), 256, 0, stream>>>(W1, w1h, w1l, 256, 64);
  transpose_split_kernel<<<dim3(8, 2, 4), 256, 0, stream>>>(W2, w2h, w2l, 256, 64);
  split_kernel<<<N_NODES * DIMC / 256, 256, 0, stream>>>(x, xh, xl, N_NODES * DIMC);

  auto layer = [&](const __hip_bfloat16* xih, const __hip_bfloat16* xil,
                   const __hip_bfloat16* wth, const __hip_bfloat16* wtl,
                   const float* av, unsigned* fmk, float* outf,
                   __hip_bfloat16* oh, __hip_bfloat16* ol) {
    gemm_kernel<<<dim3(128, 8), 256, 0, stream>>>(xih, xil, wth, wtl, hA, bpk);
    fvec_kernel<<<1024, 256, 0, stream>>>(hA, av, f1p, f2p, fmk);
    attn_kernel<<<dim3(128, 4), 512, 0, stream>>>(bpk, f1p, f2p, fmk, bits,
                                                  outf, oh, ol);
  };

  layer(xh,  xl,  w1h, w1l, a1, fme,     nullptr,        x2h, x2l);
  layer(x2h, x2l, w2h, w2l, a2, fme + 4, (float*)d_out,  nullptr, nullptr);
}

// Round 7
// 234.168 us; speedup vs baseline: 1.4502x; 1.0708x over previous
//
#include <hip/hip_runtime.h>
#include <hip/hip_bf16.h>

#define N_NODES 4096
#define DIMC    256   // H*D, also K of both layer GEMMs
#define NHEADS  4
#define LOG2E   1.44269504f

typedef __attribute__((ext_vector_type(8))) short  short8;
typedef __attribute__((ext_vector_type(4))) short  short4v;
typedef __attribute__((ext_vector_type(4))) float  float4v;

union S8U { short8 v; unsigned int u[4]; };

#if __has_builtin(__builtin_amdgcn_exp2f)
#define EXP2(x) __builtin_amdgcn_exp2f(x)
#else
#define EXP2(x) exp2f(x)
#endif

__device__ inline unsigned short bf16_bits(__hip_bfloat16 b) {
  union { __hip_bfloat16 b; unsigned short u; } cv; cv.b = b; return cv.u;
}

// monotone float<->u32 encode for atomicMax over signed floats
__device__ inline unsigned fenc(float f) {
  unsigned u = __float_as_uint(f);
  return (u & 0x80000000u) ? ~u : (u | 0x80000000u);
}
__device__ inline float fdec(unsigned k) {
  unsigned u = (k & 0x80000000u) ? (k & 0x7FFFFFFFu) : ~k;
  return __uint_as_float(u);
}

// Fragment-packed layout (operand of mfma_f32_16x16x32_bf16):
//   element (row r, k) lives at u16 index
//   ((r>>4)*8 + (k>>5))*512 + (((k>>3)&3)*16 + (r&15))*8 + (k&7)
// so a wave (lane = quad*16+col) loads one 16-row x 32-k fragment as a
// single contiguous 1-KB dwordx4 stream at frag_base + lane*8.
__device__ inline size_t packidx(int r, int k) {
  return ((size_t)(r >> 4) * 8 + (k >> 5)) * 512
       + (((k >> 3) & 3) * 16 + (r & 15)) * 8 + (k & 7);
}

// ---------------- adjacency -> bitmask (1 bit per edge) ----------------
__global__ __launch_bounds__(256) void pack_adj_kernel(
    const int* __restrict__ adj, unsigned long long* __restrict__ bits)
{
  int wid  = blockIdx.x * 4 + (threadIdx.x >> 6);
  int lane = threadIdx.x & 63;
  int row  = wid >> 6;
  int w64  = wid & 63;
  int v = adj[(size_t)row * N_NODES + w64 * 64 + lane];
  unsigned long long m = __ballot(v > 0);
  if (lane == 0) bits[row * 64 + w64] = m;
}

// ---- fp32 [4096][256] -> A-fragment-packed split bf16 (hi + lo) ---------
// thread: 8 consecutive k of one row -> one contiguous 16-B packed write.
__global__ __launch_bounds__(256) void split_pack_kernel(
    const float* __restrict__ in, unsigned short* __restrict__ hi,
    unsigned short* __restrict__ lo)
{
  int g = blockIdx.x * 256 + threadIdx.x;   // 131072 threads
  int n = g >> 5, kb = (g & 31) * 8;
  const float* ip = in + (size_t)n * DIMC + kb;
  float4v v0 = *reinterpret_cast<const float4v*>(ip);
  float4v v1 = *reinterpret_cast<const float4v*>(ip + 4);
  short8 oh, ol;
#pragma unroll
  for (int i = 0; i < 8; ++i) {
    float f = (i < 4) ? v0[i] : v1[i - 4];
    __hip_bfloat16 hb = __float2bfloat16(f);
    oh[i] = (short)bf16_bits(hb);
    ol[i] = (short)bf16_bits(__float2bfloat16(f - __bfloat162float(hb)));
  }
  size_t idx = packidx(n, kb);
  *reinterpret_cast<short8*>(hi + idx) = oh;
  *reinterpret_cast<short8*>(lo + idx) = ol;
}

// ---- W[h][f][d] -> B-fragment-packed split bf16 (col c=h*64+d, k=f) -----
// 8192 threads (32 blocks): thread does 8 k (strided reads, tiny input).
__global__ __launch_bounds__(256) void wpack_kernel(
    const float* __restrict__ W, unsigned short* __restrict__ hi,
    unsigned short* __restrict__ lo)
{
  int g = blockIdx.x * 256 + threadIdx.x;   // 8192 threads
  int c = g >> 5, kb = (g & 31) * 8;
  int h = c >> 6, d = c & 63;
  const float* wp = W + (size_t)h * DIMC * 64 + (size_t)kb * 64 + d;
  short8 oh, ol;
#pragma unroll
  for (int i = 0; i < 8; ++i) {
    float f = wp[i * 64];
    __hip_bfloat16 hb = __float2bfloat16(f);
    oh[i] = (short)bf16_bits(hb);
    ol[i] = (short)bf16_bits(__float2bfloat16(f - __bfloat162float(hb)));
  }
  size_t idx = packidx(c, kb);
  *reinterpret_cast<short8*>(hi + idx) = oh;
  *reinterpret_cast<short8*>(lo + idx) = ol;
}

// ------- h GEMM (fragment-packed split-bf16) + Bpack epilogue ------------
// All four operand streams are contiguous 1-KB wave-loads per K-step
// (no row scatter). out[n][c] fp32 row-major AND Bpack (V in MFMA
// B-fragment order for attn). grid (128,8), block 256. blockIdx.x == jt.
__global__ __launch_bounds__(256) void gemm_kernel(
    const unsigned short* __restrict__ Ah, const unsigned short* __restrict__ Al,
    const unsigned short* __restrict__ Bh, const unsigned short* __restrict__ Bl,
    float* __restrict__ out, unsigned short* __restrict__ Bpack)
{
  __shared__ float tl[32][33];
  int t = threadIdx.x;
  int wv = t >> 6, lane = t & 63, quad = lane >> 4, col = lane & 15;
  int br = blockIdx.x * 32, bc = blockIdx.y * 32;
  int rt = blockIdx.x * 2 + (wv >> 1);   // 16-row tile index
  int ct = blockIdx.y * 2 + (wv & 1);    // 16-col tile index
  int r0 = br + (wv >> 1) * 16;
  int c0 = bc + (wv & 1) * 16;
  float4v acc = {0, 0, 0, 0};
  const unsigned short* ahp = Ah + (size_t)rt * 4096 + lane * 8;
  const unsigned short* alp = Al + (size_t)rt * 4096 + lane * 8;
  const unsigned short* bhp = Bh + (size_t)ct * 4096 + lane * 8;
  const unsigned short* blp = Bl + (size_t)ct * 4096 + lane * 8;
#pragma unroll
  for (int ks = 0; ks < 8; ++ks) {
    short8 ah = *reinterpret_cast<const short8*>(ahp + ks * 512);
    short8 al = *reinterpret_cast<const short8*>(alp + ks * 512);
    short8 bh = *reinterpret_cast<const short8*>(bhp + ks * 512);
    short8 bl = *reinterpret_cast<const short8*>(blp + ks * 512);
    acc = __builtin_amdgcn_mfma_f32_16x16x32_bf16(ah, bh, acc, 0, 0, 0);
    acc = __builtin_amdgcn_mfma_f32_16x16x32_bf16(ah, bl, acc, 0, 0, 0);
    acc = __builtin_amdgcn_mfma_f32_16x16x32_bf16(al, bh, acc, 0, 0, 0);
  }
  int lr = (wv >> 1) * 16 + quad * 4, lc = (wv & 1) * 16 + col;
#pragma unroll
  for (int r = 0; r < 4; ++r) {
    out[(size_t)(r0 + quad * 4 + r) * DIMC + c0 + col] = acc[r];
    tl[lr + r][lc] = acc[r];     // tl[local_j][local_c]
  }
  __syncthreads();
  int tr = t >> 3, tc = (t & 7) * 4;   // tr: local c, tc: local j (4-wide)
  short4v oh;
#pragma unroll
  for (int k = 0; k < 4; ++k)
    oh[k] = (short)bf16_bits(__float2bfloat16(tl[tc + k][tr]));
  int c = bc + tr;
  int h = c >> 6, d = c & 63, db = d >> 4, colp = d & 15;
  int quadp = tc >> 3, jj = tc & 7;    // jj in {0,4}
  size_t fragu = (((size_t)(h * 128 + blockIdx.x) * 4 + db) * 64
                  + quadp * 16 + colp) * 8 + jj;
  *reinterpret_cast<short4v*>(Bpack + fragu) = oh;
}

// ---- f1/f2 (log2-scaled) + fused per-head global max (encoded atomic) ---
// grid 1024, block 256: wave per node.
__global__ __launch_bounds__(256) void fvec_kernel(
    const float* __restrict__ hA, const float* __restrict__ a,
    float* __restrict__ f1L, float* __restrict__ f2L,
    unsigned* __restrict__ f2enc)
{
  __shared__ float bm[4][4];  // [wave][head]
  int t = threadIdx.x, wv = t >> 6, lane = t & 63;
  int n = blockIdx.x * 4 + wv;
  int h = lane >> 4, d4 = (lane & 15) * 4;
  float4v v = *reinterpret_cast<const float4v*>(hA + (size_t)n * DIMC + lane * 4);
  const float* ah = a + h * 128;
  float s1 = v[0]*ah[d4] + v[1]*ah[d4+1] + v[2]*ah[d4+2] + v[3]*ah[d4+3];
  float s2 = v[0]*ah[64+d4] + v[1]*ah[64+d4+1] + v[2]*ah[64+d4+2] + v[3]*ah[64+d4+3];
#pragma unroll
  for (int o = 8; o >= 1; o >>= 1) {
    s1 += __shfl_xor(s1, o);
    s2 += __shfl_xor(s2, o);
  }
  float s2s = s2 * LOG2E;
  if ((lane & 15) == 0) {
    f1L[h * N_NODES + n] = s1 * LOG2E;
    f2L[h * N_NODES + n] = s2s;
    bm[wv][h] = s2s;
  }
  __syncthreads();
  if (t < 4) {
    float m = fmaxf(fmaxf(bm[0][t], bm[1][t]), fmaxf(bm[2][t], bm[3][t]));
    atomicMax(f2enc + t, fenc(m));
  }
}

// ------ fused masked-softmax attention, fragment-packed streaming --------
// grid (128, 4) = (32-row i-tile, head). block 512 = 8 waves; wave wv sweeps
// the disjoint j-range [wv*512, (wv+1)*512) for the SAME 32 i-rows, keeping
// TWO A-fragments against each B-fragment (10 MFMA per 4-KB B-load).
// __launch_bounds__(512,4): VGPR cap 128 so a whole step's loads batch
// before one wait. No barriers in the main loop. LDS reduce of the 8
// j-partials, then normalize + ELU + final write (fp32 row-major for layer
// 2 output, A-fragment-packed split-bf16 for layer 1 -> layer 2 GEMM).
__global__ __launch_bounds__(512, 4) void attn_kernel(
    const unsigned short* __restrict__ Bpack,
    const float* __restrict__ f1L, const float* __restrict__ f2L,
    const unsigned* __restrict__ f2enc,
    const unsigned long long* __restrict__ bits64, // [4096][64]
    float* __restrict__ outf, unsigned short* __restrict__ outhi,
    unsigned short* __restrict__ outlo)
{
  __shared__ float part[8][32][68];  // [wave][row][64 d + denom @64]; 69.6 KB
  int t = threadIdx.x;
  int wv = t >> 6, lane = t & 63, quad = lane >> 4, col = lane & 15;
  int it = blockIdx.x, h = blockIdx.y;
  int i0 = it * 32;
  int irow0 = i0 + col;              // rows for A-fragment 0
  int irow1 = i0 + 16 + col;         // rows for A-fragment 1

  float f2m = fdec(f2enc[h]);
  float f1i0 = f1L[h * N_NODES + irow0];
  float f1i1 = f1L[h * N_NODES + irow1];
  float s00 = f1i0 + f2m;
  float m0 = fmaxf(s00, 0.2f * s00); // lrelu monotone -> valid upper-bound shift
  float f1m0 = f1i0 - m0;
  float cm0 = -0.8f * m0;
  float s01 = f1i1 + f2m;
  float m1 = fmaxf(s01, 0.2f * s01);
  float f1m1 = f1i1 - m1;
  float cm1 = -0.8f * m1;

  const float* f2h = f2L + h * N_NODES;
  const unsigned long long* brow0 = bits64 + (size_t)irow0 * 64;
  const unsigned long long* brow1 = bits64 + (size_t)irow1 * 64;
  // wave's fragment stream: 16 steps x 4 db x 512 u16, contiguous
  const unsigned short* bp =
      Bpack + ((size_t)(h * 128 + wv * 16)) * 4 * 512 + lane * 8;
  int jbase = wv * 512;

  float4v acc0[4] = {{0,0,0,0},{0,0,0,0},{0,0,0,0},{0,0,0,0}};
  float4v acc1[4] = {{0,0,0,0},{0,0,0,0},{0,0,0,0},{0,0,0,0}};
  float4v accl0 = {0, 0, 0, 0}, accl1 = {0, 0, 0, 0};
  S8U ones;
  ones.u[0] = ones.u[1] = ones.u[2] = ones.u[3] = 0x3F803F80u; // bf16 1.0 x2

  for (int s = 0; s < 16; ++s) {     // 16 x 32-j steps, no barriers
    int j0 = jbase + s * 32;
    int sh = (j0 & 32) | (quad * 8);
    unsigned wb0 = (unsigned)(brow0[j0 >> 6] >> sh);
    unsigned wb1 = (unsigned)(brow1[j0 >> 6] >> sh);
    const float* fp = f2h + j0 + quad * 8;
    float4v fa = *reinterpret_cast<const float4v*>(fp);
    float4v fb = *reinterpret_cast<const float4v*>(fp + 4);
    const unsigned short* bs = bp + (size_t)s * 2048;
    short8 b0 = *reinterpret_cast<const short8*>(bs);
    short8 b1 = *reinterpret_cast<const short8*>(bs + 512);
    short8 b2 = *reinterpret_cast<const short8*>(bs + 1024);
    short8 b3 = *reinterpret_cast<const short8*>(bs + 1536);
    float w0[8], w1[8];
#pragma unroll
    for (int jj = 0; jj < 8; ++jj) {
      float fv = (jj < 4) ? fa[jj] : fb[jj - 4];
      float sp0 = f1m0 + fv;
      float tb0 = __builtin_fmaf(0.2f, sp0, cm0);
      float e0 = EXP2(fmaxf(sp0, tb0));
      w0[jj] = (wb0 & (1u << jj)) ? e0 : 0.0f;
      float sp1 = f1m1 + fv;
      float tb1 = __builtin_fmaf(0.2f, sp1, cm1);
      float e1 = EXP2(fmaxf(sp1, tb1));
      w1[jj] = (wb1 & (1u << jj)) ? e1 : 0.0f;
    }
    S8U afr0, afr1;
#pragma unroll
    for (int k2 = 0; k2 < 4; ++k2) { // truncate-pack two fp32 -> bf16x2
      afr0.u[k2] = __builtin_amdgcn_perm(__float_as_uint(w0[2 * k2 + 1]),
                                         __float_as_uint(w0[2 * k2]),
                                         0x07060302u);
      afr1.u[k2] = __builtin_amdgcn_perm(__float_as_uint(w1[2 * k2 + 1]),
                                         __float_as_uint(w1[2 * k2]),
                                         0x07060302u);
    }
    acc0[0] = __builtin_amdgcn_mfma_f32_16x16x32_bf16(afr0.v, b0, acc0[0], 0, 0, 0);
    acc0[1] = __builtin_amdgcn_mfma_f32_16x16x32_bf16(afr0.v, b1, acc0[1], 0, 0, 0);
    acc0[2] = __builtin_amdgcn_mfma_f32_16x16x32_bf16(afr0.v, b2, acc0[2], 0, 0, 0);
    acc0[3] = __builtin_amdgcn_mfma_f32_16x16x32_bf16(afr0.v, b3, acc0[3], 0, 0, 0);
    accl0   = __builtin_amdgcn_mfma_f32_16x16x32_bf16(afr0.v, ones.v, accl0, 0, 0, 0);
    acc1[0] = __builtin_amdgcn_mfma_f32_16x16x32_bf16(afr1.v, b0, acc1[0], 0, 0, 0);
    acc1[1] = __builtin_amdgcn_mfma_f32_16x16x32_bf16(afr1.v, b1, acc1[1], 0, 0, 0);
    acc1[2] = __builtin_amdgcn_mfma_f32_16x16x32_bf16(afr1.v, b2, acc1[2], 0, 0, 0);
    acc1[3] = __builtin_amdgcn_mfma_f32_16x16x32_bf16(afr1.v, b3, acc1[3], 0, 0, 0);
    accl1   = __builtin_amdgcn_mfma_f32_16x16x32_bf16(afr1.v, ones.v, accl1, 0, 0, 0);
  }

  // C/D layout: col=lane&15 (d sub-col), row=quad*4+reg (i). Park partials.
#pragma unroll
  for (int db = 0; db < 4; ++db)
#pragma unroll
    for (int r = 0; r < 4; ++r) {
      part[wv][quad * 4 + r][db * 16 + col] = acc0[db][r];
      part[wv][16 + quad * 4 + r][db * 16 + col] = acc1[db][r];
    }
  if (col == 0) {
#pragma unroll
    for (int r = 0; r < 4; ++r) {
      part[wv][quad * 4 + r][64] = accl0[r];
      part[wv][16 + quad * 4 + r][64] = accl1[r];
    }
  }
  __syncthreads();

  // 512 threads: t -> (row = t>>4 in 0..31, 4 d at (t&15)*4). Sum 8 partials.
  int row = t >> 4, dd = (t & 15) * 4;
  float4v s = {0, 0, 0, 0};
  float l = 0.f;
#pragma unroll
  for (int w2 = 0; w2 < 8; ++w2) {
    float4v pv = *reinterpret_cast<const float4v*>(&part[w2][row][dd]);
    s += pv;
    l += part[w2][row][64];
  }
  float rl = 1.0f / l;
  float o[4];
#pragma unroll
  for (int r = 0; r < 4; ++r) {
    float v = s[r] * rl;
    o[r] = v > 0.f ? v : EXP2(v * LOG2E) - 1.0f;
  }
  int n2 = i0 + row;
  if (outf) {
    size_t oo = (size_t)n2 * DIMC + h * 64 + dd;
    *reinterpret_cast<float4v*>(outf + oo) = {o[0], o[1], o[2], o[3]};
  } else {
    int cg = h * 64 + dd;            // global col (multiple of 4)
    size_t pidx = packidx(n2, cg);   // A-fragment-packed for layer-2 GEMM
    short4v ohv, olv;
#pragma unroll
    for (int r = 0; r < 4; ++r) {
      __hip_bfloat16 hb = __float2bfloat16(o[r]);
      ohv[r] = (short)bf16_bits(hb);
      olv[r] = (short)bf16_bits(__float2bfloat16(o[r] - __bfloat162float(hb)));
    }
    *reinterpret_cast<short4v*>(outhi + pidx) = ohv;
    *reinterpret_cast<short4v*>(outlo + pidx) = olv;
  }
}

extern "C" void kernel_launch(void* const* d_in, const int* in_sizes, int n_in,
                              void* d_out, int out_size, void* d_ws, size_t ws_size,
                              hipStream_t stream)
{
  // inputs: t, x, adj, W1, a1, W2, a2  (fp32 except adj int32)
  const float* x   = (const float*)d_in[1];
  const int*   adj = (const int*)d_in[2];
  const float* W1  = (const float*)d_in[3];
  const float* a1  = (const float*)d_in[4];
  const float* W2  = (const float*)d_in[5];
  const float* a2  = (const float*)d_in[6];

  char* ws = (char*)d_ws;
  size_t off = 0;
  auto alloc = [&](size_t b) { size_t o = off; off = (off + b + 255) & ~255ULL; return o; };
  size_t o_bits = alloc((size_t)N_NODES * 64 * 8);          // 2 MB bitmask
  size_t o_w1h  = alloc((size_t)DIMC * DIMC * 2);           // packed weights
  size_t o_w1l  = alloc((size_t)DIMC * DIMC * 2);
  size_t o_w2h  = alloc((size_t)DIMC * DIMC * 2);
  size_t o_w2l  = alloc((size_t)DIMC * DIMC * 2);
  size_t o_xh   = alloc((size_t)N_NODES * DIMC * 2);        // packed A operand
  size_t o_xl   = alloc((size_t)N_NODES * DIMC * 2);
  size_t o_hA   = alloc((size_t)N_NODES * DIMC * 4);        // h fp32 row-major
  size_t o_bp   = alloc((size_t)N_NODES * DIMC * 2);        // Bpack (2 MB)
  size_t o_x2h  = alloc((size_t)N_NODES * DIMC * 2);        // packed layer-2 A
  size_t o_x2l  = alloc((size_t)N_NODES * DIMC * 2);
  size_t o_f1   = alloc((size_t)NHEADS * N_NODES * 4);
  size_t o_f2   = alloc((size_t)NHEADS * N_NODES * 4);
  size_t o_fm   = alloc(256);                               // 2 layers x 4 u32 (encoded max)

  unsigned long long* bits = (unsigned long long*)(ws + o_bits);
  unsigned short* w1h = (unsigned short*)(ws + o_w1h);
  unsigned short* w1l = (unsigned short*)(ws + o_w1l);
  unsigned short* w2h = (unsigned short*)(ws + o_w2h);
  unsigned short* w2l = (unsigned short*)(ws + o_w2l);
  unsigned short* xh  = (unsigned short*)(ws + o_xh);
  unsigned short* xl  = (unsigned short*)(ws + o_xl);
  float*          hA  = (float*)(ws + o_hA);
  unsigned short* bpk = (unsigned short*)(ws + o_bp);
  unsigned short* x2h = (unsigned short*)(ws + o_x2h);
  unsigned short* x2l = (unsigned short*)(ws + o_x2l);
  float* f1p = (float*)(ws + o_f1);
  float* f2p = (float*)(ws + o_f2);
  unsigned* fme = (unsigned*)(ws + o_fm);

  hipMemsetAsync(ws + o_fm, 0, 64, stream);  // encoded-max init (monotone min)
  pack_adj_kernel<<<N_NODES * 64 / 4, 256, 0, stream>>>(adj, bits);
  wpack_kernel<<<32, 256, 0, stream>>>(W1, w1h, w1l);
  wpack_kernel<<<32, 256, 0, stream>>>(W2, w2h, w2l);
  split_pack_kernel<<<N_NODES * DIMC / 8 / 256, 256, 0, stream>>>(x, xh, xl);

  auto layer = [&](const unsigned short* xih, const unsigned short* xil,
                   const unsigned short* wth, const unsigned short* wtl,
                   const float* av, unsigned* fmk, float* outf,
                   unsigned short* oh, unsigned short* ol) {
    gemm_kernel<<<dim3(128, 8), 256, 0, stream>>>(xih, xil, wth, wtl, hA, bpk);
    fvec_kernel<<<1024, 256, 0, stream>>>(hA, av, f1p, f2p, fmk);
    attn_kernel<<<dim3(128, 4), 512, 0, stream>>>(bpk, f1p, f2p, fmk, bits,
                                                  outf, oh, ol);
  };

  layer(xh,  xl,  w1h, w1l, a1, fme,     nullptr,        x2h, x2l);
  layer(x2h, x2l, w2h, w2l, a2, fme + 4, (float*)d_out,  nullptr, nullptr);
}

// Round 8
// 217.645 us; speedup vs baseline: 1.5603x; 1.0759x over previous
//
#include <hip/hip_runtime.h>
#include <hip/hip_bf16.h>

#define N_NODES 4096
#define DIMC    256   // H*D, also K of both layer GEMMs
#define NHEADS  4
#define LOG2E   1.44269504f

typedef __attribute__((ext_vector_type(8))) short  short8;
typedef __attribute__((ext_vector_type(4))) short  short4v;
typedef __attribute__((ext_vector_type(4))) float  float4v;

union S8U { short8 v; unsigned int u[4]; };

#if __has_builtin(__builtin_amdgcn_exp2f)
#define EXP2(x) __builtin_amdgcn_exp2f(x)
#else
#define EXP2(x) exp2f(x)
#endif

__device__ inline unsigned short bf16_bits(__hip_bfloat16 b) {
  union { __hip_bfloat16 b; unsigned short u; } cv; cv.b = b; return cv.u;
}

// monotone float<->u32 encode for atomicMax over signed floats
__device__ inline unsigned fenc(float f) {
  unsigned u = __float_as_uint(f);
  return (u & 0x80000000u) ? ~u : (u | 0x80000000u);
}
__device__ inline float fdec(unsigned k) {
  unsigned u = (k & 0x80000000u) ? (k & 0x7FFFFFFFu) : ~k;
  return __uint_as_float(u);
}

// Fragment-packed layout (operand of mfma_f32_16x16x32_bf16):
//   element (row r, k) lives at u16 index
//   ((r>>4)*8 + (k>>5))*512 + (((k>>3)&3)*16 + (r&15))*8 + (k&7)
// so a wave (lane = quad*16+col) loads one 16-row x 32-k fragment as a
// single contiguous 1-KB dwordx4 stream at frag_base + lane*8.
__device__ inline size_t packidx(int r, int k) {
  return ((size_t)(r >> 4) * 8 + (k >> 5)) * 512
       + (((k >> 3) & 3) * 16 + (r & 15)) * 8 + (k & 7);
}

// ---------------- adjacency -> bitmask (1 bit per edge) ----------------
__global__ __launch_bounds__(256) void pack_adj_kernel(
    const int* __restrict__ adj, unsigned long long* __restrict__ bits)
{
  int wid  = blockIdx.x * 4 + (threadIdx.x >> 6);
  int lane = threadIdx.x & 63;
  int row  = wid >> 6;
  int w64  = wid & 63;
  int v = adj[(size_t)row * N_NODES + w64 * 64 + lane];
  unsigned long long m = __ballot(v > 0);
  if (lane == 0) bits[row * 64 + w64] = m;
}

// ---- fp32 [4096][256] -> A-fragment-packed split bf16 (hi + lo) ---------
// thread: 8 consecutive k of one row -> one contiguous 16-B packed write.
__global__ __launch_bounds__(256) void split_pack_kernel(
    const float* __restrict__ in, unsigned short* __restrict__ hi,
    unsigned short* __restrict__ lo)
{
  int g = blockIdx.x * 256 + threadIdx.x;   // 131072 threads
  int n = g >> 5, kb = (g & 31) * 8;
  const float* ip = in + (size_t)n * DIMC + kb;
  float4v v0 = *reinterpret_cast<const float4v*>(ip);
  float4v v1 = *reinterpret_cast<const float4v*>(ip + 4);
  short8 oh, ol;
#pragma unroll
  for (int i = 0; i < 8; ++i) {
    float f = (i < 4) ? v0[i] : v1[i - 4];
    __hip_bfloat16 hb = __float2bfloat16(f);
    oh[i] = (short)bf16_bits(hb);
    ol[i] = (short)bf16_bits(__float2bfloat16(f - __bfloat162float(hb)));
  }
  size_t idx = packidx(n, kb);
  *reinterpret_cast<short8*>(hi + idx) = oh;
  *reinterpret_cast<short8*>(lo + idx) = ol;
}

// ---- W[h][f][d] -> B-fragment-packed split bf16 (col c=h*64+d, k=f) -----
// Both layers in one launch: grid (32, 2); blockIdx.y selects W1/W2.
__global__ __launch_bounds__(256) void wpack_kernel(
    const float* __restrict__ W1, const float* __restrict__ W2,
    unsigned short* __restrict__ h1, unsigned short* __restrict__ l1,
    unsigned short* __restrict__ h2, unsigned short* __restrict__ l2)
{
  const float* W = blockIdx.y ? W2 : W1;
  unsigned short* hi = blockIdx.y ? h2 : h1;
  unsigned short* lo = blockIdx.y ? l2 : l1;
  int g = blockIdx.x * 256 + threadIdx.x;   // 8192 threads per layer
  int c = g >> 5, kb = (g & 31) * 8;
  int h = c >> 6, d = c & 63;
  const float* wp = W + (size_t)h * DIMC * 64 + (size_t)kb * 64 + d;
  short8 oh, ol;
#pragma unroll
  for (int i = 0; i < 8; ++i) {
    float f = wp[i * 64];
    __hip_bfloat16 hb = __float2bfloat16(f);
    oh[i] = (short)bf16_bits(hb);
    ol[i] = (short)bf16_bits(__float2bfloat16(f - __bfloat162float(hb)));
  }
  size_t idx = packidx(c, kb);
  *reinterpret_cast<short8*>(hi + idx) = oh;
  *reinterpret_cast<short8*>(lo + idx) = ol;
}

// ------- h GEMM (fragment-packed split-bf16) + Bpack epilogue ------------
// All four operand streams are contiguous 1-KB wave-loads per K-step
// (no row scatter). out[n][c] fp32 row-major AND Bpack (V in MFMA
// B-fragment order for attn). grid (128,8), block 256. blockIdx.x == jt.
__global__ __launch_bounds__(256) void gemm_kernel(
    const unsigned short* __restrict__ Ah, const unsigned short* __restrict__ Al,
    const unsigned short* __restrict__ Bh, const unsigned short* __restrict__ Bl,
    float* __restrict__ out, unsigned short* __restrict__ Bpack)
{
  __shared__ float tl[32][33];
  int t = threadIdx.x;
  int wv = t >> 6, lane = t & 63, quad = lane >> 4, col = lane & 15;
  int br = blockIdx.x * 32, bc = blockIdx.y * 32;
  int rt = blockIdx.x * 2 + (wv >> 1);   // 16-row tile index
  int ct = blockIdx.y * 2 + (wv & 1);    // 16-col tile index
  int r0 = br + (wv >> 1) * 16;
  int c0 = bc + (wv & 1) * 16;
  float4v acc = {0, 0, 0, 0};
  const unsigned short* ahp = Ah + (size_t)rt * 4096 + lane * 8;
  const unsigned short* alp = Al + (size_t)rt * 4096 + lane * 8;
  const unsigned short* bhp = Bh + (size_t)ct * 4096 + lane * 8;
  const unsigned short* blp = Bl + (size_t)ct * 4096 + lane * 8;
#pragma unroll
  for (int ks = 0; ks < 8; ++ks) {
    short8 ah = *reinterpret_cast<const short8*>(ahp + ks * 512);
    short8 al = *reinterpret_cast<const short8*>(alp + ks * 512);
    short8 bh = *reinterpret_cast<const short8*>(bhp + ks * 512);
    short8 bl = *reinterpret_cast<const short8*>(blp + ks * 512);
    acc = __builtin_amdgcn_mfma_f32_16x16x32_bf16(ah, bh, acc, 0, 0, 0);
    acc = __builtin_amdgcn_mfma_f32_16x16x32_bf16(ah, bl, acc, 0, 0, 0);
    acc = __builtin_amdgcn_mfma_f32_16x16x32_bf16(al, bh, acc, 0, 0, 0);
  }
  int lr = (wv >> 1) * 16 + quad * 4, lc = (wv & 1) * 16 + col;
#pragma unroll
  for (int r = 0; r < 4; ++r) {
    out[(size_t)(r0 + quad * 4 + r) * DIMC + c0 + col] = acc[r];
    tl[lr + r][lc] = acc[r];     // tl[local_j][local_c]
  }
  __syncthreads();
  int tr = t >> 3, tc = (t & 7) * 4;   // tr: local c, tc: local j (4-wide)
  short4v oh;
#pragma unroll
  for (int k = 0; k < 4; ++k)
    oh[k] = (short)bf16_bits(__float2bfloat16(tl[tc + k][tr]));
  int c = bc + tr;
  int h = c >> 6, d = c & 63, db = d >> 4, colp = d & 15;
  int quadp = tc >> 3, jj = tc & 7;    // jj in {0,4}
  size_t fragu = (((size_t)(h * 128 + blockIdx.x) * 4 + db) * 64
                  + quadp * 16 + colp) * 8 + jj;
  *reinterpret_cast<short4v*>(Bpack + fragu) = oh;
}

// ---- f1/f2 (log2-scaled) + fused per-head global max (encoded atomic) ---
// grid 1024, block 256: wave per node.
__global__ __launch_bounds__(256) void fvec_kernel(
    const float* __restrict__ hA, const float* __restrict__ a,
    float* __restrict__ f1L, float* __restrict__ f2L,
    unsigned* __restrict__ f2enc)
{
  __shared__ float bm[4][4];  // [wave][head]
  int t = threadIdx.x, wv = t >> 6, lane = t & 63;
  int n = blockIdx.x * 4 + wv;
  int h = lane >> 4, d4 = (lane & 15) * 4;
  float4v v = *reinterpret_cast<const float4v*>(hA + (size_t)n * DIMC + lane * 4);
  const float* ah = a + h * 128;
  float s1 = v[0]*ah[d4] + v[1]*ah[d4+1] + v[2]*ah[d4+2] + v[3]*ah[d4+3];
  float s2 = v[0]*ah[64+d4] + v[1]*ah[64+d4+1] + v[2]*ah[64+d4+2] + v[3]*ah[64+d4+3];
#pragma unroll
  for (int o = 8; o >= 1; o >>= 1) {
    s1 += __shfl_xor(s1, o);
    s2 += __shfl_xor(s2, o);
  }
  float s2s = s2 * LOG2E;
  if ((lane & 15) == 0) {
    f1L[h * N_NODES + n] = s1 * LOG2E;
    f2L[h * N_NODES + n] = s2s;
    bm[wv][h] = s2s;
  }
  __syncthreads();
  if (t < 4) {
    float m = fmaxf(fmaxf(bm[0][t], bm[1][t]), fmaxf(bm[2][t], bm[3][t]));
    atomicMax(f2enc + t, fenc(m));
  }
}

// ------ fused masked-softmax attention, fragment-packed streaming --------
// grid (128, 4) = (32-row i-tile, head). block 512 = 8 waves; wave wv sweeps
// the disjoint j-range [wv*512, (wv+1)*512) for the SAME 32 i-rows, keeping
// TWO A-fragments against each B-fragment (10 MFMA per 4-KB B-load).
// Masks for all 32 rows x 64 tiles (16 KB) are preloaded ONCE into LDS
// (aliased into the part[] buffer; parts are only written after the loop):
// the per-step mask access becomes a conflict-free ds_read_b64 broadcast
// instead of a 16-segment global scatter (2x/step) -- the last scattered
// access in the loop. All remaining global traffic is contiguous 1-KB
// B-streams + 32-B f2 segments. No barriers in the main loop.
__global__ __launch_bounds__(512, 4) void attn_kernel(
    const unsigned short* __restrict__ Bpack,
    const float* __restrict__ f1L, const float* __restrict__ f2L,
    const unsigned* __restrict__ f2enc,
    const unsigned long long* __restrict__ bits64, // [4096][64]
    float* __restrict__ outf, unsigned short* __restrict__ outhi,
    unsigned short* __restrict__ outlo)
{
  __shared__ __align__(16) float part[8][32][68];  // 69.6 KB (also mask alias)
  unsigned long long* lds_bits =
      reinterpret_cast<unsigned long long*>(&part[0][0][0]); // [64 tiles][32 rows]
  int t = threadIdx.x;
  int wv = t >> 6, lane = t & 63, quad = lane >> 4, col = lane & 15;
  int it = blockIdx.x, h = blockIdx.y;
  int i0 = it * 32;
  int irow0 = i0 + col;              // rows for A-fragment 0
  int irow1 = i0 + 16 + col;         // rows for A-fragment 1

  // ---- mask preload: 32 rows x 64 tiles, coalesced read, [tile][row] LDS
  {
    int rr = t >> 4, tt = (t & 15) * 4;
    const unsigned long long* gsrc = bits64 + (size_t)(i0 + rr) * 64 + tt;
    unsigned long long m0 = gsrc[0], m1 = gsrc[1], m2 = gsrc[2], m3 = gsrc[3];
    lds_bits[(tt + 0) * 32 + rr] = m0;
    lds_bits[(tt + 1) * 32 + rr] = m1;
    lds_bits[(tt + 2) * 32 + rr] = m2;
    lds_bits[(tt + 3) * 32 + rr] = m3;
  }

  float f2m = fdec(f2enc[h]);
  float f1i0 = f1L[h * N_NODES + irow0];
  float f1i1 = f1L[h * N_NODES + irow1];
  float s00 = f1i0 + f2m;
  float m0 = fmaxf(s00, 0.2f * s00); // lrelu monotone -> valid upper-bound shift
  float f1m0 = f1i0 - m0;
  float cm0 = -0.8f * m0;
  float s01 = f1i1 + f2m;
  float m1 = fmaxf(s01, 0.2f * s01);
  float f1m1 = f1i1 - m1;
  float cm1 = -0.8f * m1;

  const float* f2h = f2L + h * N_NODES;
  // wave's fragment stream: 16 steps x 4 db x 512 u16, contiguous
  const unsigned short* bp =
      Bpack + ((size_t)(h * 128 + wv * 16)) * 4 * 512 + lane * 8;
  int jbase = wv * 512;

  float4v acc0[4] = {{0,0,0,0},{0,0,0,0},{0,0,0,0},{0,0,0,0}};
  float4v acc1[4] = {{0,0,0,0},{0,0,0,0},{0,0,0,0},{0,0,0,0}};
  float4v accl0 = {0, 0, 0, 0}, accl1 = {0, 0, 0, 0};
  S8U ones;
  ones.u[0] = ones.u[1] = ones.u[2] = ones.u[3] = 0x3F803F80u; // bf16 1.0 x2

  __syncthreads();                   // masks resident before first use

  for (int s = 0; s < 16; ++s) {     // 16 x 32-j steps, no barriers
    int j0 = jbase + s * 32;
    int tg = j0 >> 6;                // global mask tile = wv*8 + (s>>1)
    unsigned long long wq0 = lds_bits[tg * 32 + col];
    unsigned long long wq1 = lds_bits[tg * 32 + col + 16];
    int sh = (j0 & 32) | (quad * 8);
    unsigned wb0 = (unsigned)(wq0 >> sh);
    unsigned wb1 = (unsigned)(wq1 >> sh);
    const float* fp = f2h + j0 + quad * 8;
    float4v fa = *reinterpret_cast<const float4v*>(fp);
    float4v fb = *reinterpret_cast<const float4v*>(fp + 4);
    const unsigned short* bs = bp + (size_t)s * 2048;
    short8 b0 = *reinterpret_cast<const short8*>(bs);
    short8 b1 = *reinterpret_cast<const short8*>(bs + 512);
    short8 b2 = *reinterpret_cast<const short8*>(bs + 1024);
    short8 b3 = *reinterpret_cast<const short8*>(bs + 1536);
    float w0[8], w1[8];
#pragma unroll
    for (int jj = 0; jj < 8; ++jj) {
      float fv = (jj < 4) ? fa[jj] : fb[jj - 4];
      float sp0 = f1m0 + fv;
      float tb0 = __builtin_fmaf(0.2f, sp0, cm0);
      float e0 = EXP2(fmaxf(sp0, tb0));
      w0[jj] = (wb0 & (1u << jj)) ? e0 : 0.0f;
      float sp1 = f1m1 + fv;
      float tb1 = __builtin_fmaf(0.2f, sp1, cm1);
      float e1 = EXP2(fmaxf(sp1, tb1));
      w1[jj] = (wb1 & (1u << jj)) ? e1 : 0.0f;
    }
    S8U afr0, afr1;
#pragma unroll
    for (int k2 = 0; k2 < 4; ++k2) { // truncate-pack two fp32 -> bf16x2
      afr0.u[k2] = __builtin_amdgcn_perm(__float_as_uint(w0[2 * k2 + 1]),
                                         __float_as_uint(w0[2 * k2]),
                                         0x07060302u);
      afr1.u[k2] = __builtin_amdgcn_perm(__float_as_uint(w1[2 * k2 + 1]),
                                         __float_as_uint(w1[2 * k2]),
                                         0x07060302u);
    }
    acc0[0] = __builtin_amdgcn_mfma_f32_16x16x32_bf16(afr0.v, b0, acc0[0], 0, 0, 0);
    acc0[1] = __builtin_amdgcn_mfma_f32_16x16x32_bf16(afr0.v, b1, acc0[1], 0, 0, 0);
    acc0[2] = __builtin_amdgcn_mfma_f32_16x16x32_bf16(afr0.v, b2, acc0[2], 0, 0, 0);
    acc0[3] = __builtin_amdgcn_mfma_f32_16x16x32_bf16(afr0.v, b3, acc0[3], 0, 0, 0);
    accl0   = __builtin_amdgcn_mfma_f32_16x16x32_bf16(afr0.v, ones.v, accl0, 0, 0, 0);
    acc1[0] = __builtin_amdgcn_mfma_f32_16x16x32_bf16(afr1.v, b0, acc1[0], 0, 0, 0);
    acc1[1] = __builtin_amdgcn_mfma_f32_16x16x32_bf16(afr1.v, b1, acc1[1], 0, 0, 0);
    acc1[2] = __builtin_amdgcn_mfma_f32_16x16x32_bf16(afr1.v, b2, acc1[2], 0, 0, 0);
    acc1[3] = __builtin_amdgcn_mfma_f32_16x16x32_bf16(afr1.v, b3, acc1[3], 0, 0, 0);
    accl1   = __builtin_amdgcn_mfma_f32_16x16x32_bf16(afr1.v, ones.v, accl1, 0, 0, 0);
  }

  __syncthreads();   // all mask reads complete before aliased part writes

  // C/D layout: col=lane&15 (d sub-col), row=quad*4+reg (i). Park partials.
#pragma unroll
  for (int db = 0; db < 4; ++db)
#pragma unroll
    for (int r = 0; r < 4; ++r) {
      part[wv][quad * 4 + r][db * 16 + col] = acc0[db][r];
      part[wv][16 + quad * 4 + r][db * 16 + col] = acc1[db][r];
    }
  if (col == 0) {
#pragma unroll
    for (int r = 0; r < 4; ++r) {
      part[wv][quad * 4 + r][64] = accl0[r];
      part[wv][16 + quad * 4 + r][64] = accl1[r];
    }
  }
  __syncthreads();

  // 512 threads: t -> (row = t>>4 in 0..31, 4 d at (t&15)*4). Sum 8 partials.
  int row = t >> 4, dd = (t & 15) * 4;
  float4v s = {0, 0, 0, 0};
  float l = 0.f;
#pragma unroll
  for (int w2 = 0; w2 < 8; ++w2) {
    float4v pv = *reinterpret_cast<const float4v*>(&part[w2][row][dd]);
    s += pv;
    l += part[w2][row][64];
  }
  float rl = 1.0f / l;
  float o[4];
#pragma unroll
  for (int r = 0; r < 4; ++r) {
    float v = s[r] * rl;
    o[r] = v > 0.f ? v : EXP2(v * LOG2E) - 1.0f;
  }
  int n2 = i0 + row;
  if (outf) {
    size_t oo = (size_t)n2 * DIMC + h * 64 + dd;
    *reinterpret_cast<float4v*>(outf + oo) = {o[0], o[1], o[2], o[3]};
  } else {
    int cg = h * 64 + dd;            // global col (multiple of 4)
    size_t pidx = packidx(n2, cg);   // A-fragment-packed for layer-2 GEMM
    short4v ohv, olv;
#pragma unroll
    for (int r = 0; r < 4; ++r) {
      __hip_bfloat16 hb = __float2bfloat16(o[r]);
      ohv[r] = (short)bf16_bits(hb);
      olv[r] = (short)bf16_bits(__float2bfloat16(o[r] - __bfloat162float(hb)));
    }
    *reinterpret_cast<short4v*>(outhi + pidx) = ohv;
    *reinterpret_cast<short4v*>(outlo + pidx) = olv;
  }
}

extern "C" void kernel_launch(void* const* d_in, const int* in_sizes, int n_in,
                              void* d_out, int out_size, void* d_ws, size_t ws_size,
                              hipStream_t stream)
{
  // inputs: t, x, adj, W1, a1, W2, a2  (fp32 except adj int32)
  const float* x   = (const float*)d_in[1];
  const int*   adj = (const int*)d_in[2];
  const float* W1  = (const float*)d_in[3];
  const float* a1  = (const float*)d_in[4];
  const float* W2  = (const float*)d_in[5];
  const float* a2  = (const float*)d_in[6];

  char* ws = (char*)d_ws;
  size_t off = 0;
  auto alloc = [&](size_t b) { size_t o = off; off = (off + b + 255) & ~255ULL; return o; };
  size_t o_bits = alloc((size_t)N_NODES * 64 * 8);          // 2 MB bitmask
  size_t o_w1h  = alloc((size_t)DIMC * DIMC * 2);           // packed weights
  size_t o_w1l  = alloc((size_t)DIMC * DIMC * 2);
  size_t o_w2h  = alloc((size_t)DIMC * DIMC * 2);
  size_t o_w2l  = alloc((size_t)DIMC * DIMC * 2);
  size_t o_xh   = alloc((size_t)N_NODES * DIMC * 2);        // packed A operand
  size_t o_xl   = alloc((size_t)N_NODES * DIMC * 2);
  size_t o_hA   = alloc((size_t)N_NODES * DIMC * 4);        // h fp32 row-major
  size_t o_bp   = alloc((size_t)N_NODES * DIMC * 2);        // Bpack (2 MB)
  size_t o_x2h  = alloc((size_t)N_NODES * DIMC * 2);        // packed layer-2 A
  size_t o_x2l  = alloc((size_t)N_NODES * DIMC * 2);
  size_t o_f1   = alloc((size_t)NHEADS * N_NODES * 4);
  size_t o_f2   = alloc((size_t)NHEADS * N_NODES * 4);
  size_t o_fm   = alloc(256);                               // 2 layers x 4 u32 (encoded max)

  unsigned long long* bits = (unsigned long long*)(ws + o_bits);
  unsigned short* w1h = (unsigned short*)(ws + o_w1h);
  unsigned short* w1l = (unsigned short*)(ws + o_w1l);
  unsigned short* w2h = (unsigned short*)(ws + o_w2h);
  unsigned short* w2l = (unsigned short*)(ws + o_w2l);
  unsigned short* xh  = (unsigned short*)(ws + o_xh);
  unsigned short* xl  = (unsigned short*)(ws + o_xl);
  float*          hA  = (float*)(ws + o_hA);
  unsigned short* bpk = (unsigned short*)(ws + o_bp);
  unsigned short* x2h = (unsigned short*)(ws + o_x2h);
  unsigned short* x2l = (unsigned short*)(ws + o_x2l);
  float* f1p = (float*)(ws + o_f1);
  float* f2p = (float*)(ws + o_f2);
  unsigned* fme = (unsigned*)(ws + o_fm);

  hipMemsetAsync(ws + o_fm, 0, 64, stream);  // encoded-max init (monotone min)
  pack_adj_kernel<<<N_NODES * 64 / 4, 256, 0, stream>>>(adj, bits);
  wpack_kernel<<<dim3(32, 2), 256, 0, stream>>>(W1, W2, w1h, w1l, w2h, w2l);
  split_pack_kernel<<<N_NODES * DIMC / 8 / 256, 256, 0, stream>>>(x, xh, xl);

  auto layer = [&](const unsigned short* xih, const unsigned short* xil,
                   const unsigned short* wth, const unsigned short* wtl,
                   const float* av, unsigned* fmk, float* outf,
                   unsigned short* oh, unsigned short* ol) {
    gemm_kernel<<<dim3(128, 8), 256, 0, stream>>>(xih, xil, wth, wtl, hA, bpk);
    fvec_kernel<<<1024, 256, 0, stream>>>(hA, av, f1p, f2p, fmk);
    attn_kernel<<<dim3(128, 4), 512, 0, stream>>>(bpk, f1p, f2p, fmk, bits,
                                                  outf, oh, ol);
  };

  layer(xh,  xl,  w1h, w1l, a1, fme,     nullptr,        x2h, x2l);
  layer(x2h, x2l, w2h, w2l, a2, fme + 4, (float*)d_out,  nullptr, nullptr);
}

// Round 9
// 187.930 us; speedup vs baseline: 1.8070x; 1.1581x over previous
//
#include <hip/hip_runtime.h>
#include <hip/hip_bf16.h>

#define N_NODES 4096
#define DIMC    256   // H*D, also K of both layer GEMMs
#define NHEADS  4
#define LOG2E   1.44269504f

typedef __attribute__((ext_vector_type(8))) short  short8;
typedef __attribute__((ext_vector_type(4))) short  short4v;
typedef __attribute__((ext_vector_type(4))) float  float4v;

union S8U { short8 v; unsigned int u[4]; };

#if __has_builtin(__builtin_amdgcn_exp2f)
#define EXP2(x) __builtin_amdgcn_exp2f(x)
#else
#define EXP2(x) exp2f(x)
#endif

__device__ inline unsigned short bf16_bits(__hip_bfloat16 b) {
  union { __hip_bfloat16 b; unsigned short u; } cv; cv.b = b; return cv.u;
}

// Fragment-packed layout (operand of mfma_f32_16x16x32_bf16):
//   element (row r, k) lives at u16 index
//   ((r>>4)*8 + (k>>5))*512 + (((k>>3)&3)*16 + (r&15))*8 + (k&7)
// so a wave (lane = quad*16+col) loads one 16-row x 32-k fragment as a
// single contiguous 1-KB dwordx4 stream at frag_base + lane*8.
__device__ inline size_t packidx(int r, int k) {
  return ((size_t)(r >> 4) * 8 + (k >> 5)) * 512
       + (((k >> 3) & 3) * 16 + (r & 15)) * 8 + (k & 7);
}

// ------------- fused preprocessing: one dispatch, 4 phases ---------------
//  blocks [0, 65536)          : adjacency -> bitmask
//  blocks [65536, 66048)      : x fp32 -> A-fragment-packed split bf16
//  blocks [66048, 66112)      : W1/W2 -> B-fragment-packed split bf16
//  blocks [66112, 66176)      : zero the f1/f2 accumulators (256 KB)
__global__ __launch_bounds__(256) void prep_kernel(
    const int* __restrict__ adj, unsigned long long* __restrict__ bits,
    const float* __restrict__ x,
    unsigned short* __restrict__ xh, unsigned short* __restrict__ xl,
    const float* __restrict__ W1, const float* __restrict__ W2,
    unsigned short* __restrict__ w1h, unsigned short* __restrict__ w1l,
    unsigned short* __restrict__ w2h, unsigned short* __restrict__ w2l,
    float* __restrict__ f12zero)
{
  int b = blockIdx.x, t = threadIdx.x;
  if (b < 65536) {                      // ---- pack_adj
    int wid  = b * 4 + (t >> 6);
    int lane = t & 63;
    int row  = wid >> 6;
    int w64  = wid & 63;
    int v = adj[(size_t)row * N_NODES + w64 * 64 + lane];
    unsigned long long m = __ballot(v > 0);
    if (lane == 0) bits[row * 64 + w64] = m;
  } else if (b < 66048) {               // ---- split_pack (x)
    int g = (b - 65536) * 256 + t;      // 131072 threads
    int n = g >> 5, kb = (g & 31) * 8;
    const float* ip = x + (size_t)n * DIMC + kb;
    float4v v0 = *reinterpret_cast<const float4v*>(ip);
    float4v v1 = *reinterpret_cast<const float4v*>(ip + 4);
    short8 oh, ol;
#pragma unroll
    for (int i = 0; i < 8; ++i) {
      float f = (i < 4) ? v0[i] : v1[i - 4];
      __hip_bfloat16 hb = __float2bfloat16(f);
      oh[i] = (short)bf16_bits(hb);
      ol[i] = (short)bf16_bits(__float2bfloat16(f - __bfloat162float(hb)));
    }
    size_t idx = packidx(n, kb);
    *reinterpret_cast<short8*>(xh + idx) = oh;
    *reinterpret_cast<short8*>(xl + idx) = ol;
  } else if (b < 66112) {               // ---- wpack (W1 / W2)
    int bid = b - 66048;
    const float* W = (bid >> 5) ? W2 : W1;
    unsigned short* hi = (bid >> 5) ? w2h : w1h;
    unsigned short* lo = (bid >> 5) ? w2l : w1l;
    int g = (bid & 31) * 256 + t;       // 8192 threads per layer
    int c = g >> 5, kb = (g & 31) * 8;
    int h = c >> 6, d = c & 63;
    const float* wp = W + (size_t)h * DIMC * 64 + (size_t)kb * 64 + d;
    short8 oh, ol;
#pragma unroll
    for (int i = 0; i < 8; ++i) {
      float f = wp[i * 64];
      __hip_bfloat16 hb = __float2bfloat16(f);
      oh[i] = (short)bf16_bits(hb);
      ol[i] = (short)bf16_bits(__float2bfloat16(f - __bfloat162float(hb)));
    }
    size_t idx = packidx(c, kb);
    *reinterpret_cast<short8*>(hi + idx) = oh;
    *reinterpret_cast<short8*>(lo + idx) = ol;
  } else {                              // ---- zero f1/f2 (256 KB)
    int z = b - 66112;                  // 0..63
    reinterpret_cast<float4v*>(f12zero)[(size_t)z * 256 + t] = {0, 0, 0, 0};
  }
}

// ------- h GEMM (fragment-packed split-bf16) + f-vec + Bpack epilogue ----
// All four operand streams are contiguous 1-KB wave-loads per K-step.
// Epilogue 1: f1/f2 partials (dot of acc with a-vec halves over this
//   block's 16-col slices) via 16-lane shfl reduce + atomicAdd (LOG2E-
//   scaled). Replaces the fvec kernel; hA never goes to memory.
// Epilogue 2: Bpack (V in MFMA B-fragment order for attn).
// grid (128,8), block 256. blockIdx.x == jt, head = blockIdx.y>>1.
__global__ __launch_bounds__(256) void gemm_kernel(
    const unsigned short* __restrict__ Ah, const unsigned short* __restrict__ Al,
    const unsigned short* __restrict__ Bh, const unsigned short* __restrict__ Bl,
    const float* __restrict__ avec,
    float* __restrict__ f1L, float* __restrict__ f2L,
    unsigned short* __restrict__ Bpack)
{
  __shared__ float tl[32][33];
  int t = threadIdx.x;
  int wv = t >> 6, lane = t & 63, quad = lane >> 4, col = lane & 15;
  int bc = blockIdx.y * 32;
  int rt = blockIdx.x * 2 + (wv >> 1);   // 16-row tile index
  int ct = blockIdx.y * 2 + (wv & 1);    // 16-col tile index
  int r0 = blockIdx.x * 32 + (wv >> 1) * 16;
  int c0 = bc + (wv & 1) * 16;
  float4v acc = {0, 0, 0, 0};
  const unsigned short* ahp = Ah + (size_t)rt * 4096 + lane * 8;
  const unsigned short* alp = Al + (size_t)rt * 4096 + lane * 8;
  const unsigned short* bhp = Bh + (size_t)ct * 4096 + lane * 8;
  const unsigned short* blp = Bl + (size_t)ct * 4096 + lane * 8;
#pragma unroll
  for (int ks = 0; ks < 8; ++ks) {
    short8 ah = *reinterpret_cast<const short8*>(ahp + ks * 512);
    short8 al = *reinterpret_cast<const short8*>(alp + ks * 512);
    short8 bh = *reinterpret_cast<const short8*>(bhp + ks * 512);
    short8 bl = *reinterpret_cast<const short8*>(blp + ks * 512);
    acc = __builtin_amdgcn_mfma_f32_16x16x32_bf16(ah, bh, acc, 0, 0, 0);
    acc = __builtin_amdgcn_mfma_f32_16x16x32_bf16(ah, bl, acc, 0, 0, 0);
    acc = __builtin_amdgcn_mfma_f32_16x16x32_bf16(al, bh, acc, 0, 0, 0);
  }

  // ---- f1/f2 partial reduction (this block's 16-col slice of head hh)
  int hh = blockIdx.y >> 1;
  int d0 = (c0 + col) & 63;
  float av1 = avec[hh * 128 + d0];
  float av2 = avec[hh * 128 + 64 + d0];
#pragma unroll
  for (int r = 0; r < 4; ++r) {
    float v1 = acc[r] * av1;
    float v2 = acc[r] * av2;
#pragma unroll
    for (int o = 8; o >= 1; o >>= 1) {
      v1 += __shfl_xor(v1, o);
      v2 += __shfl_xor(v2, o);
    }
    if ((lane & 15) == 0) {
      int n = r0 + quad * 4 + r;
      atomicAdd(f1L + hh * N_NODES + n, v1 * LOG2E);
      atomicAdd(f2L + hh * N_NODES + n, v2 * LOG2E);
    }
  }

  // ---- Bpack epilogue (via LDS transpose of the 32x32 tile)
  int lr = (wv >> 1) * 16 + quad * 4, lc = (wv & 1) * 16 + col;
#pragma unroll
  for (int r = 0; r < 4; ++r) tl[lr + r][lc] = acc[r];
  __syncthreads();
  int tr = t >> 3, tc = (t & 7) * 4;   // tr: local c, tc: local j (4-wide)
  short4v oh;
#pragma unroll
  for (int k = 0; k < 4; ++k)
    oh[k] = (short)bf16_bits(__float2bfloat16(tl[tc + k][tr]));
  int c = bc + tr;
  int h = c >> 6, d = c & 63, db = d >> 4, colp = d & 15;
  int quadp = tc >> 3, jj = tc & 7;    // jj in {0,4}
  size_t fragu = (((size_t)(h * 128 + blockIdx.x) * 4 + db) * 64
                  + quadp * 16 + colp) * 8 + jj;
  *reinterpret_cast<short4v*>(Bpack + fragu) = oh;
}

// ------ fused masked-softmax attention, fragment-packed streaming --------
// grid (128, 4) = (32-row i-tile, head). block 512 = 8 waves; wave wv sweeps
// the disjoint j-range [wv*512, (wv+1)*512) for the SAME 32 i-rows, keeping
// TWO A-fragments against each B-fragment (10 MFMA per 4-KB B-load).
// Prologue (replaces fvec's global max): masks for 32 rows x 64 tiles
// (16 KB) preloaded to LDS; per-head f2 max (16 KB column) reduced through
// LDS. Main loop barrier-free; all global traffic contiguous.
__global__ __launch_bounds__(512, 4) void attn_kernel(
    const unsigned short* __restrict__ Bpack,
    const float* __restrict__ f1L, const float* __restrict__ f2L,
    const unsigned long long* __restrict__ bits64, // [4096][64]
    float* __restrict__ outf, unsigned short* __restrict__ outhi,
    unsigned short* __restrict__ outlo)
{
  __shared__ __align__(16) float part[8][32][68];  // 69.6 KB (aliased below)
  unsigned long long* lds_bits =
      reinterpret_cast<unsigned long long*>(&part[0][0][0]); // 16 KB: [tile][row]
  float* red = reinterpret_cast<float*>(&part[2][0][0]);     // 2 KB @ 17408
  int t = threadIdx.x;
  int wv = t >> 6, lane = t & 63, quad = lane >> 4, col = lane & 15;
  int it = blockIdx.x, h = blockIdx.y;
  int i0 = it * 32;
  int irow0 = i0 + col;              // rows for A-fragment 0
  int irow1 = i0 + 16 + col;         // rows for A-fragment 1

  // ---- mask preload: 32 rows x 64 tiles, coalesced read, [tile][row] LDS
  {
    int rr = t >> 4, tt = (t & 15) * 4;
    const unsigned long long* gsrc = bits64 + (size_t)(i0 + rr) * 64 + tt;
    unsigned long long m0 = gsrc[0], m1 = gsrc[1], m2 = gsrc[2], m3 = gsrc[3];
    lds_bits[(tt + 0) * 32 + rr] = m0;
    lds_bits[(tt + 1) * 32 + rr] = m1;
    lds_bits[(tt + 2) * 32 + rr] = m2;
    lds_bits[(tt + 3) * 32 + rr] = m3;
  }

  // ---- per-head f2 max over all 4096 nodes (LDS tree)
  const float* f2h = f2L + h * N_NODES;
  {
    float4v ma = *reinterpret_cast<const float4v*>(f2h + t * 8);
    float4v mb = *reinterpret_cast<const float4v*>(f2h + t * 8 + 4);
    red[t] = fmaxf(fmaxf(fmaxf(ma[0], ma[1]), fmaxf(ma[2], ma[3])),
                   fmaxf(fmaxf(mb[0], mb[1]), fmaxf(mb[2], mb[3])));
  }
  __syncthreads();
#pragma unroll
  for (int s2 = 256; s2 >= 1; s2 >>= 1) {
    if (t < s2) red[t] = fmaxf(red[t], red[t + s2]);
    __syncthreads();
  }
  float f2m = red[0];

  float f1i0 = f1L[h * N_NODES + irow0];
  float f1i1 = f1L[h * N_NODES + irow1];
  float s00 = f1i0 + f2m;
  float m0 = fmaxf(s00, 0.2f * s00); // lrelu monotone -> valid upper-bound shift
  float f1m0 = f1i0 - m0;
  float cm0 = -0.8f * m0;
  float s01 = f1i1 + f2m;
  float m1 = fmaxf(s01, 0.2f * s01);
  float f1m1 = f1i1 - m1;
  float cm1 = -0.8f * m1;

  // wave's fragment stream: 16 steps x 4 db x 512 u16, contiguous
  const unsigned short* bp =
      Bpack + ((size_t)(h * 128 + wv * 16)) * 4 * 512 + lane * 8;
  int jbase = wv * 512;

  float4v acc0[4] = {{0,0,0,0},{0,0,0,0},{0,0,0,0},{0,0,0,0}};
  float4v acc1[4] = {{0,0,0,0},{0,0,0,0},{0,0,0,0},{0,0,0,0}};
  float4v accl0 = {0, 0, 0, 0}, accl1 = {0, 0, 0, 0};
  S8U ones;
  ones.u[0] = ones.u[1] = ones.u[2] = ones.u[3] = 0x3F803F80u; // bf16 1.0 x2

  for (int s = 0; s < 16; ++s) {     // 16 x 32-j steps, no barriers
    int j0 = jbase + s * 32;
    int tg = j0 >> 6;                // global mask tile = wv*8 + (s>>1)
    unsigned long long wq0 = lds_bits[tg * 32 + col];
    unsigned long long wq1 = lds_bits[tg * 32 + col + 16];
    int sh = (j0 & 32) | (quad * 8);
    unsigned wb0 = (unsigned)(wq0 >> sh);
    unsigned wb1 = (unsigned)(wq1 >> sh);
    const float* fp = f2h + j0 + quad * 8;
    float4v fa = *reinterpret_cast<const float4v*>(fp);
    float4v fb = *reinterpret_cast<const float4v*>(fp + 4);
    const unsigned short* bs = bp + (size_t)s * 2048;
    short8 b0 = *reinterpret_cast<const short8*>(bs);
    short8 b1 = *reinterpret_cast<const short8*>(bs + 512);
    short8 b2 = *reinterpret_cast<const short8*>(bs + 1024);
    short8 b3 = *reinterpret_cast<const short8*>(bs + 1536);
    float w0[8], w1[8];
#pragma unroll
    for (int jj = 0; jj < 8; ++jj) {
      float fv = (jj < 4) ? fa[jj] : fb[jj - 4];
      float sp0 = f1m0 + fv;
      float tb0 = __builtin_fmaf(0.2f, sp0, cm0);
      float e0 = EXP2(fmaxf(sp0, tb0));
      w0[jj] = (wb0 & (1u << jj)) ? e0 : 0.0f;
      float sp1 = f1m1 + fv;
      float tb1 = __builtin_fmaf(0.2f, sp1, cm1);
      float e1 = EXP2(fmaxf(sp1, tb1));
      w1[jj] = (wb1 & (1u << jj)) ? e1 : 0.0f;
    }
    S8U afr0, afr1;
#pragma unroll
    for (int k2 = 0; k2 < 4; ++k2) { // truncate-pack two fp32 -> bf16x2
      afr0.u[k2] = __builtin_amdgcn_perm(__float_as_uint(w0[2 * k2 + 1]),
                                         __float_as_uint(w0[2 * k2]),
                                         0x07060302u);
      afr1.u[k2] = __builtin_amdgcn_perm(__float_as_uint(w1[2 * k2 + 1]),
                                         __float_as_uint(w1[2 * k2]),
                                         0x07060302u);
    }
    acc0[0] = __builtin_amdgcn_mfma_f32_16x16x32_bf16(afr0.v, b0, acc0[0], 0, 0, 0);
    acc0[1] = __builtin_amdgcn_mfma_f32_16x16x32_bf16(afr0.v, b1, acc0[1], 0, 0, 0);
    acc0[2] = __builtin_amdgcn_mfma_f32_16x16x32_bf16(afr0.v, b2, acc0[2], 0, 0, 0);
    acc0[3] = __builtin_amdgcn_mfma_f32_16x16x32_bf16(afr0.v, b3, acc0[3], 0, 0, 0);
    accl0   = __builtin_amdgcn_mfma_f32_16x16x32_bf16(afr0.v, ones.v, accl0, 0, 0, 0);
    acc1[0] = __builtin_amdgcn_mfma_f32_16x16x32_bf16(afr1.v, b0, acc1[0], 0, 0, 0);
    acc1[1] = __builtin_amdgcn_mfma_f32_16x16x32_bf16(afr1.v, b1, acc1[1], 0, 0, 0);
    acc1[2] = __builtin_amdgcn_mfma_f32_16x16x32_bf16(afr1.v, b2, acc1[2], 0, 0, 0);
    acc1[3] = __builtin_amdgcn_mfma_f32_16x16x32_bf16(afr1.v, b3, acc1[3], 0, 0, 0);
    accl1   = __builtin_amdgcn_mfma_f32_16x16x32_bf16(afr1.v, ones.v, accl1, 0, 0, 0);
  }

  __syncthreads();   // all mask/red reads complete before aliased part writes

  // C/D layout: col=lane&15 (d sub-col), row=quad*4+reg (i). Park partials.
#pragma unroll
  for (int db = 0; db < 4; ++db)
#pragma unroll
    for (int r = 0; r < 4; ++r) {
      part[wv][quad * 4 + r][db * 16 + col] = acc0[db][r];
      part[wv][16 + quad * 4 + r][db * 16 + col] = acc1[db][r];
    }
  if (col == 0) {
#pragma unroll
    for (int r = 0; r < 4; ++r) {
      part[wv][quad * 4 + r][64] = accl0[r];
      part[wv][16 + quad * 4 + r][64] = accl1[r];
    }
  }
  __syncthreads();

  // 512 threads: t -> (row = t>>4 in 0..31, 4 d at (t&15)*4). Sum 8 partials.
  int row = t >> 4, dd = (t & 15) * 4;
  float4v s = {0, 0, 0, 0};
  float l = 0.f;
#pragma unroll
  for (int w2 = 0; w2 < 8; ++w2) {
    float4v pv = *reinterpret_cast<const float4v*>(&part[w2][row][dd]);
    s += pv;
    l += part[w2][row][64];
  }
  float rl = 1.0f / l;
  float o[4];
#pragma unroll
  for (int r = 0; r < 4; ++r) {
    float v = s[r] * rl;
    o[r] = v > 0.f ? v : EXP2(v * LOG2E) - 1.0f;
  }
  int n2 = i0 + row;
  if (outf) {
    size_t oo = (size_t)n2 * DIMC + h * 64 + dd;
    *reinterpret_cast<float4v*>(outf + oo) = {o[0], o[1], o[2], o[3]};
  } else {
    int cg = h * 64 + dd;            // global col (multiple of 4)
    size_t pidx = packidx(n2, cg);   // A-fragment-packed for layer-2 GEMM
    short4v ohv, olv;
#pragma unroll
    for (int r = 0; r < 4; ++r) {
      __hip_bfloat16 hb = __float2bfloat16(o[r]);
      ohv[r] = (short)bf16_bits(hb);
      olv[r] = (short)bf16_bits(__float2bfloat16(o[r] - __bfloat162float(hb)));
    }
    *reinterpret_cast<short4v*>(outhi + pidx) = ohv;
    *reinterpret_cast<short4v*>(outlo + pidx) = olv;
  }
}

extern "C" void kernel_launch(void* const* d_in, const int* in_sizes, int n_in,
                              void* d_out, int out_size, void* d_ws, size_t ws_size,
                              hipStream_t stream)
{
  // inputs: t, x, adj, W1, a1, W2, a2  (fp32 except adj int32)
  const float* x   = (const float*)d_in[1];
  const int*   adj = (const int*)d_in[2];
  const float* W1  = (const float*)d_in[3];
  const float* a1  = (const float*)d_in[4];
  const float* W2  = (const float*)d_in[5];
  const float* a2  = (const float*)d_in[6];

  char* ws = (char*)d_ws;
  size_t off = 0;
  auto alloc = [&](size_t b) { size_t o = off; off = (off + b + 255) & ~255ULL; return o; };
  size_t o_bits = alloc((size_t)N_NODES * 64 * 8);          // 2 MB bitmask
  size_t o_w1h  = alloc((size_t)DIMC * DIMC * 2);           // packed weights
  size_t o_w1l  = alloc((size_t)DIMC * DIMC * 2);
  size_t o_w2h  = alloc((size_t)DIMC * DIMC * 2);
  size_t o_w2l  = alloc((size_t)DIMC * DIMC * 2);
  size_t o_xh   = alloc((size_t)N_NODES * DIMC * 2);        // packed A operand
  size_t o_xl   = alloc((size_t)N_NODES * DIMC * 2);
  size_t o_bp   = alloc((size_t)N_NODES * DIMC * 2);        // Bpack (2 MB)
  size_t o_x2h  = alloc((size_t)N_NODES * DIMC * 2);        // packed layer-2 A
  size_t o_x2l  = alloc((size_t)N_NODES * DIMC * 2);
  size_t o_f12  = alloc((size_t)4 * NHEADS * N_NODES * 4);  // f1a,f2a,f1b,f2b (256 KB)

  unsigned long long* bits = (unsigned long long*)(ws + o_bits);
  unsigned short* w1h = (unsigned short*)(ws + o_w1h);
  unsigned short* w1l = (unsigned short*)(ws + o_w1l);
  unsigned short* w2h = (unsigned short*)(ws + o_w2h);
  unsigned short* w2l = (unsigned short*)(ws + o_w2l);
  unsigned short* xh  = (unsigned short*)(ws + o_xh);
  unsigned short* xl  = (unsigned short*)(ws + o_xl);
  unsigned short* bpk = (unsigned short*)(ws + o_bp);
  unsigned short* x2h = (unsigned short*)(ws + o_x2h);
  unsigned short* x2l = (unsigned short*)(ws + o_x2l);
  float* f12 = (float*)(ws + o_f12);
  float* f1a = f12;
  float* f2a = f12 + NHEADS * N_NODES;
  float* f1b = f12 + 2 * NHEADS * N_NODES;
  float* f2b = f12 + 3 * NHEADS * N_NODES;

  prep_kernel<<<66176, 256, 0, stream>>>(adj, bits, x, xh, xl, W1, W2,
                                         w1h, w1l, w2h, w2l, f12);

  auto layer = [&](const unsigned short* xih, const unsigned short* xil,
                   const unsigned short* wth, const unsigned short* wtl,
                   const float* av, float* f1p, float* f2p, float* outf,
                   unsigned short* oh, unsigned short* ol) {
    gemm_kernel<<<dim3(128, 8), 256, 0, stream>>>(xih, xil, wth, wtl, av,
                                                  f1p, f2p, bpk);
    attn_kernel<<<dim3(128, 4), 512, 0, stream>>>(bpk, f1p, f2p, bits,
                                                  outf, oh, ol);
  };

  layer(xh,  xl,  w1h, w1l, a1, f1a, f2a, nullptr,       x2h, x2l);
  layer(x2h, x2l, w2h, w2l, a2, f1b, f2b, (float*)d_out, nullptr, nullptr);
}